// Round 1
// baseline (3670.083 us; speedup 1.0000x reference)
//
#include <hip/hip_runtime.h>
#include <hip/hip_bf16.h>
#include <math.h>

#define BB   4
#define TT   1024
#define DD   1024
#define HH   16
#define DII  2048
#define DSS  16
#define DCC  4
#define KK   204
#define HDD  64
#define DTRR 64

// ---------------- reduction helpers ----------------
__device__ __forceinline__ float wave_sum(float v) {
#pragma unroll
  for (int o = 32; o > 0; o >>= 1) v += __shfl_xor(v, o, 64);
  return v;
}
__device__ __forceinline__ float wave_max(float v) {
#pragma unroll
  for (int o = 32; o > 0; o >>= 1) v = fmaxf(v, __shfl_xor(v, o, 64));
  return v;
}
// 256-thread block sum; sh must be __shared__ float[4]
__device__ __forceinline__ float block_sum256(float v, volatile float* sh) {
  v = wave_sum(v);
  if ((threadIdx.x & 63) == 0) sh[threadIdx.x >> 6] = v;
  __syncthreads();
  float r = sh[0] + sh[1] + sh[2] + sh[3];
  __syncthreads();
  return r;
}

// ---------------- layernorm ----------------
__global__ __launch_bounds__(256) void layernorm_kernel(
    const float* __restrict__ x, const float* __restrict__ g,
    const float* __restrict__ be, float* __restrict__ xn) {
  __shared__ float sh[4];
  int row = blockIdx.x;
  const float* xr = x + (size_t)row * DD;
  float v[4];
  float s = 0.f;
#pragma unroll
  for (int i = 0; i < 4; i++) { v[i] = xr[threadIdx.x + 256 * i]; s += v[i]; }
  float mean = block_sum256(s, sh) * (1.f / DD);
  float q = 0.f;
#pragma unroll
  for (int i = 0; i < 4; i++) { float d = v[i] - mean; q += d * d; }
  float var = block_sum256(q, sh) * (1.f / DD);
  float rstd = rsqrtf(var + 1e-5f);
  float* xo = xn + (size_t)row * DD;
#pragma unroll
  for (int i = 0; i < 4; i++) {
    int c = threadIdx.x + 256 * i;
    xo[c] = (v[i] - mean) * rstd * g[c] + be[c];
  }
}

// ---------------- generic fp32 GEMM: C = act(A@B + bias) ----------------
// A [M,Kd] lda, B [Kd,N] ldb, C [M,N] ldc. act: 0 none, 1 relu, 2 softplus
__global__ __launch_bounds__(256) void gemm_f32(
    const float* __restrict__ A, int lda,
    const float* __restrict__ B, int ldb,
    float* __restrict__ C, int ldc,
    int M, int N, int Kd,
    const float* __restrict__ bias, int act) {
  __shared__ float As[16][65];
  __shared__ float Bs[16][65];
  int tx = threadIdx.x % 16;
  int ty = threadIdx.x / 16;
  int row0 = blockIdx.y * 64, col0 = blockIdx.x * 64;
  float acc[4][4] = {};
  int ar = threadIdx.x / 4;
  int ak = (threadIdx.x % 4) * 4;
  int bc = threadIdx.x % 64;
  int br = threadIdx.x / 64;
  for (int k0 = 0; k0 < Kd; k0 += 16) {
#pragma unroll
    for (int i = 0; i < 4; i++) {
      int gr = row0 + ar, gk = k0 + ak + i;
      float v = 0.f;
      if (gr < M && gk < Kd) v = A[(size_t)gr * lda + gk];
      As[ak + i][ar] = v;
    }
#pragma unroll
    for (int i = 0; i < 4; i++) {
      int gk = k0 + br + 4 * i, gc = col0 + bc;
      float v = 0.f;
      if (gk < Kd && gc < N) v = B[(size_t)gk * ldb + gc];
      Bs[br + 4 * i][bc] = v;
    }
    __syncthreads();
#pragma unroll
    for (int kk = 0; kk < 16; kk++) {
      float a[4], b[4];
#pragma unroll
      for (int i = 0; i < 4; i++) a[i] = As[kk][ty * 4 + i];
#pragma unroll
      for (int j = 0; j < 4; j++) b[j] = Bs[kk][tx * 4 + j];
#pragma unroll
      for (int i = 0; i < 4; i++)
#pragma unroll
        for (int j = 0; j < 4; j++) acc[i][j] += a[i] * b[j];
    }
    __syncthreads();
  }
#pragma unroll
  for (int i = 0; i < 4; i++) {
    int r = row0 + ty * 4 + i;
    if (r >= M) continue;
#pragma unroll
    for (int j = 0; j < 4; j++) {
      int c = col0 + tx * 4 + j;
      if (c >= N) continue;
      float v = acc[i][j];
      if (bias) v += bias[c];
      if (act == 1) v = fmaxf(v, 0.f);
      else if (act == 2) v = (v > 20.f) ? v : log1pf(__expf(v));
      C[(size_t)r * ldc + c] = v;
    }
  }
}

// ---------------- router score: scores[row] = h[row,:]·Wr2 + br2 ----------------
__global__ __launch_bounds__(256) void router_score_kernel(
    const float* __restrict__ h, const float* __restrict__ Wr2,
    const float* __restrict__ br2, float* __restrict__ scores) {
  __shared__ float sh[4];
  int row = blockIdx.x;
  float v = h[(size_t)row * 256 + threadIdx.x] * Wr2[threadIdx.x];
  float s = block_sum256(v, sh);
  if (threadIdx.x == 0) scores[row] = s + br2[0];
}

// ---------------- exact top-K per batch via bitonic sort (desc, idx tiebreak) ----------------
__global__ __launch_bounds__(1024) void topk_kernel(
    const float* __restrict__ scores, int* __restrict__ idx) {
  __shared__ float s[1024];
  __shared__ int si[1024];
  int b = blockIdx.x, t = threadIdx.x;
  s[t] = scores[b * TT + t];
  si[t] = t;
  __syncthreads();
  for (int k = 2; k <= 1024; k <<= 1) {
    for (int j = k >> 1; j > 0; j >>= 1) {
      int partner = t ^ j;
      if (partner > t) {
        bool dirDesc = ((t & k) == 0);
        float s1 = s[t], s2 = s[partner];
        int i1 = si[t], i2 = si[partner];
        bool firstGreater = (s1 > s2) || (s1 == s2 && i1 < i2);
        bool doSwap = dirDesc ? !firstGreater : firstGreater;
        if (doSwap) { s[t] = s2; s[partner] = s1; si[t] = i2; si[partner] = i1; }
      }
      __syncthreads();
    }
  }
  if (t < KK) idx[b * KK + t] = si[t];
}

// ---------------- causal conv (DC=4) + silu ----------------
__global__ __launch_bounds__(256) void conv_silu_kernel(
    const float* __restrict__ uz, const float* __restrict__ conv_w,
    const float* __restrict__ conv_b, float* __restrict__ u) {
  size_t gid = (size_t)blockIdx.x * 256 + threadIdx.x;  // over B*T*DI
  int c = gid % DII;
  size_t bt = gid / DII;
  int t = bt % TT;
  int b = bt / TT;
  float sum = conv_b[c];
#pragma unroll
  for (int j = 0; j < DCC; j++) {
    int tt = t - (DCC - 1) + j;
    if (tt >= 0) sum += uz[((size_t)(b * TT + tt)) * (2 * DII) + c] * conv_w[c * DCC + j];
  }
  u[gid] = sum / (1.f + __expf(-sum));
}

// ---------------- selective scan: one thread per (b, di) ----------------
__global__ __launch_bounds__(256) void ssm_scan_kernel(
    const float* __restrict__ dt, const float* __restrict__ proj,
    const float* __restrict__ u, const float* __restrict__ uz,
    const float* __restrict__ A_log, const float* __restrict__ Dskip,
    float* __restrict__ y) {
  int gid = blockIdx.x * 256 + threadIdx.x;  // 0 .. BB*DII-1
  int di = gid % DII;
  int b = gid / DII;
  float a[DSS];
#pragma unroll
  for (int s = 0; s < DSS; s++) a[s] = -__expf(A_log[di * DSS + s]);
  float hst[DSS];
#pragma unroll
  for (int s = 0; s < DSS; s++) hst[s] = 0.f;
  float dsk = Dskip[di];
  for (int t = 0; t < TT; t++) {
    size_t bt = (size_t)(b * TT + t);
    float dtv = dt[bt * DII + di];
    float uv = u[bt * DII + di];
    float zv = uz[bt * (2 * DII) + DII + di];
    const float* pr = proj + bt * 96 + DTRR;  // B at [0..15], C at [16..31]
    float dtu = dtv * uv;
    float yt = 0.f;
#pragma unroll
    for (int s = 0; s < DSS; s++) {
      float dA = __expf(dtv * a[s]);
      hst[s] = dA * hst[s] + dtu * pr[s];
      yt += hst[s] * pr[DSS + s];
    }
    float sz = zv / (1.f + __expf(-zv));
    y[bt * DII + di] = (yt + uv * dsk) * sz;
  }
}

// ---------------- gather selected tokens ----------------
__global__ __launch_bounds__(256) void gather_tok(
    const float* __restrict__ xn, const int* __restrict__ idx,
    float* __restrict__ tok) {
  int r = blockIdx.x;  // 0..BB*KK-1
  int b = r / KK;
  int tsel = idx[r];
  const float* src = xn + ((size_t)(b * TT + tsel)) * DD;
  float* dst = tok + (size_t)r * DD;
#pragma unroll
  for (int j = 0; j < 4; j++) dst[threadIdx.x + 256 * j] = src[threadIdx.x + 256 * j];
}

// ---------------- attention: one wave per (b,h,query) ----------------
__global__ __launch_bounds__(64) void attn_kernel(
    const float* __restrict__ qkv, float* __restrict__ attn_o) {
  int gid = blockIdx.x;
  int qi = gid % KK;
  int bh = gid / KK;
  int h = bh % HH;
  int b = bh / HH;
  __shared__ float qs[64];
  __shared__ float p[KK];
  int tid = threadIdx.x;
  qs[tid] = qkv[((size_t)(b * KK + qi)) * 3072 + h * 64 + tid];
  __syncthreads();
  float pmax = -1e30f;
  for (int j = tid; j < KK; j += 64) {
    const float* kr = qkv + ((size_t)(b * KK + j)) * 3072 + 1024 + h * 64;
    float s = 0.f;
#pragma unroll
    for (int d = 0; d < 64; d++) s += qs[d] * kr[d];
    s *= 0.125f;  // 1/sqrt(64)
    p[j] = s;
    pmax = fmaxf(pmax, s);
  }
  pmax = wave_max(pmax);
  __syncthreads();
  float lsum = 0.f;
  for (int j = tid; j < KK; j += 64) {
    float e = __expf(p[j] - pmax);
    p[j] = e;
    lsum += e;
  }
  lsum = wave_sum(lsum);
  __syncthreads();
  float inv = 1.f / lsum;
  float acc = 0.f;
  for (int j = 0; j < KK; j++)
    acc += p[j] * qkv[((size_t)(b * KK + j)) * 3072 + 2048 + h * 64 + tid];
  attn_o[((size_t)(b * KK + qi)) * DD + h * 64 + tid] = acc * inv;
}

// ---------------- out = x + delta_ssm ----------------
__global__ __launch_bounds__(256) void add_kernel(
    const float* __restrict__ x, const float* __restrict__ d,
    float* __restrict__ out, int n) {
  int i = blockIdx.x * 256 + threadIdx.x;
  if (i < n) out[i] = x[i] + d[i];
}

// ---------------- scatter: out[b, idx, :] = x + delta_tok ----------------
__global__ __launch_bounds__(256) void scatter_kernel(
    const float* __restrict__ x, const float* __restrict__ attnd,
    const int* __restrict__ idx, float* __restrict__ out) {
  int r = blockIdx.x;  // 0..BB*KK-1
  int b = r / KK;
  int tsel = idx[r];
  size_t drow = ((size_t)(b * TT + tsel)) * DD;
  const float* ds = attnd + (size_t)r * DD;
#pragma unroll
  for (int j = 0; j < 4; j++) {
    int c = threadIdx.x + 256 * j;
    out[drow + c] = x[drow + c] + ds[c];
  }
}

extern "C" void kernel_launch(void* const* d_in, const int* in_sizes, int n_in,
                              void* d_out, int out_size, void* d_ws, size_t ws_size,
                              hipStream_t stream) {
  const float* x = (const float*)d_in[0];
  const float* ln_g = (const float*)d_in[1];
  const float* ln_b = (const float*)d_in[2];
  const float* Wr1 = (const float*)d_in[3];
  const float* br1 = (const float*)d_in[4];
  const float* Wr2 = (const float*)d_in[5];
  const float* br2 = (const float*)d_in[6];
  const float* Wqkv = (const float*)d_in[7];
  const float* bqkv = (const float*)d_in[8];
  const float* Wo = (const float*)d_in[9];
  const float* bo = (const float*)d_in[10];
  const float* W_in = (const float*)d_in[11];
  const float* conv_w = (const float*)d_in[12];
  const float* conv_b = (const float*)d_in[13];
  const float* W_xproj = (const float*)d_in[14];
  const float* W_dt = (const float*)d_in[15];
  const float* b_dt = (const float*)d_in[16];
  const float* A_log = (const float*)d_in[17];
  const float* Dskip = (const float*)d_in[18];
  const float* W_out = (const float*)d_in[19];
  float* out = (float*)d_out;

  float* w = (float*)d_ws;
  size_t o = 0;
  float* xn = w + o;     o += (size_t)BB * TT * DD;        // 4.19M
  float* hbuf = w + o;   o += (size_t)BB * TT * 256;       // 1.05M (reused: attn delta)
  float* scores = w + o; o += (size_t)BB * TT;             // 4K
  int* idxb = (int*)(w + o); o += 1024;                    // 816 ints
  float* uzb = w + o;    o += (size_t)BB * TT * 2 * DII;   // 16.8M
  float* ub = w + o;     o += (size_t)BB * TT * DII;       // 8.39M
  float* projb = w + o;  o += (size_t)BB * TT * 96;        // 0.39M
  float* dtb = w + o;    o += (size_t)BB * TT * DII;       // 8.39M (reused: ssm delta)
  float* yb = w + o;     o += (size_t)BB * TT * DII;       // 8.39M
  float* tokb = w + o;   o += (size_t)BB * KK * DD;        // 0.84M
  float* qkvb = w + o;   o += (size_t)BB * KK * 3 * DD;    // 2.51M
  float* attno = w + o;  o += (size_t)BB * KK * DD;        // 0.84M
  float* ssmdb = dtb;   // reuse (dt dead after scan)
  float* attnd = hbuf;  // reuse (h dead after router)

  // 1. layernorm
  layernorm_kernel<<<BB * TT, 256, 0, stream>>>(x, ln_g, ln_b, xn);
  // 2. router
  gemm_f32<<<dim3(4, 64), 256, 0, stream>>>(xn, DD, Wr1, 256, hbuf, 256,
                                            BB * TT, 256, DD, br1, 1);
  router_score_kernel<<<BB * TT, 256, 0, stream>>>(hbuf, Wr2, br2, scores);
  topk_kernel<<<BB, 1024, 0, stream>>>(scores, idxb);
  // 3. SSM branch
  gemm_f32<<<dim3(64, 64), 256, 0, stream>>>(xn, DD, W_in, 2 * DII, uzb, 2 * DII,
                                             BB * TT, 2 * DII, DD, nullptr, 0);
  conv_silu_kernel<<<(BB * TT * DII) / 256, 256, 0, stream>>>(uzb, conv_w, conv_b, ub);
  gemm_f32<<<dim3(2, 64), 256, 0, stream>>>(ub, DII, W_xproj, 96, projb, 96,
                                            BB * TT, 96, DII, nullptr, 0);
  gemm_f32<<<dim3(32, 64), 256, 0, stream>>>(projb, 96, W_dt, DII, dtb, DII,
                                             BB * TT, DII, DTRR, b_dt, 2);
  ssm_scan_kernel<<<(BB * DII) / 256, 256, 0, stream>>>(dtb, projb, ub, uzb,
                                                        A_log, Dskip, yb);
  gemm_f32<<<dim3(16, 64), 256, 0, stream>>>(yb, DII, W_out, DD, ssmdb, DD,
                                             BB * TT, DD, DII, nullptr, 0);
  add_kernel<<<(BB * TT * DD) / 256, 256, 0, stream>>>(x, ssmdb, out, BB * TT * DD);
  // 4. attention branch on selected tokens
  gather_tok<<<BB * KK, 256, 0, stream>>>(xn, idxb, tokb);
  gemm_f32<<<dim3(48, 13), 256, 0, stream>>>(tokb, DD, Wqkv, 3 * DD, qkvb, 3 * DD,
                                             BB * KK, 3 * DD, DD, bqkv, 0);
  attn_kernel<<<BB * HH * KK, 64, 0, stream>>>(qkvb, attno);
  gemm_f32<<<dim3(16, 13), 256, 0, stream>>>(attno, DD, Wo, DD, attnd, DD,
                                             BB * KK, DD, DD, bo, 0);
  // 5. scatter attention rows over ssm rows
  scatter_kernel<<<BB * KK, 256, 0, stream>>>(x, attnd, idxb, out);
}

// Round 2
// 2691.642 us; speedup vs baseline: 1.3635x; 1.3635x over previous
//
#include <hip/hip_runtime.h>
#include <hip/hip_bf16.h>
#include <math.h>

#define BB   4
#define TT   1024
#define DD   1024
#define HH   16
#define DII  2048
#define DSS  16
#define DCC  4
#define KK   204
#define HDD  64
#define DTRR 64
#define NCH  8
#define LCH  128   // TT / NCH

// ---------------- reduction helpers ----------------
__device__ __forceinline__ float wave_sum(float v) {
#pragma unroll
  for (int o = 32; o > 0; o >>= 1) v += __shfl_xor(v, o, 64);
  return v;
}
__device__ __forceinline__ float wave_max(float v) {
#pragma unroll
  for (int o = 32; o > 0; o >>= 1) v = fmaxf(v, __shfl_xor(v, o, 64));
  return v;
}
// 256-thread block sum; sh must be __shared__ float[4]
__device__ __forceinline__ float block_sum256(float v, volatile float* sh) {
  v = wave_sum(v);
  if ((threadIdx.x & 63) == 0) sh[threadIdx.x >> 6] = v;
  __syncthreads();
  float r = sh[0] + sh[1] + sh[2] + sh[3];
  __syncthreads();
  return r;
}

// ---------------- layernorm ----------------
__global__ __launch_bounds__(256) void layernorm_kernel(
    const float* __restrict__ x, const float* __restrict__ g,
    const float* __restrict__ be, float* __restrict__ xn) {
  __shared__ float sh[4];
  int row = blockIdx.x;
  const float* xr = x + (size_t)row * DD;
  float v[4];
  float s = 0.f;
#pragma unroll
  for (int i = 0; i < 4; i++) { v[i] = xr[threadIdx.x + 256 * i]; s += v[i]; }
  float mean = block_sum256(s, sh) * (1.f / DD);
  float q = 0.f;
#pragma unroll
  for (int i = 0; i < 4; i++) { float d = v[i] - mean; q += d * d; }
  float var = block_sum256(q, sh) * (1.f / DD);
  float rstd = rsqrtf(var + 1e-5f);
  float* xo = xn + (size_t)row * DD;
#pragma unroll
  for (int i = 0; i < 4; i++) {
    int c = threadIdx.x + 256 * i;
    xo[c] = (v[i] - mean) * rstd * g[c] + be[c];
  }
}

// ---------------- generic fp32 GEMM: C = act(A@B + bias) ----------------
// A [M,Kd] lda, B [Kd,N] ldb, C [M,N] ldc. act: 0 none, 1 relu, 2 softplus
__global__ __launch_bounds__(256) void gemm_f32(
    const float* __restrict__ A, int lda,
    const float* __restrict__ B, int ldb,
    float* __restrict__ C, int ldc,
    int M, int N, int Kd,
    const float* __restrict__ bias, int act) {
  __shared__ float As[16][65];
  __shared__ float Bs[16][65];
  int tx = threadIdx.x % 16;
  int ty = threadIdx.x / 16;
  int row0 = blockIdx.y * 64, col0 = blockIdx.x * 64;
  float acc[4][4] = {};
  int ar = threadIdx.x / 4;
  int ak = (threadIdx.x % 4) * 4;
  int bc = threadIdx.x % 64;
  int br = threadIdx.x / 64;
  for (int k0 = 0; k0 < Kd; k0 += 16) {
#pragma unroll
    for (int i = 0; i < 4; i++) {
      int gr = row0 + ar, gk = k0 + ak + i;
      float v = 0.f;
      if (gr < M && gk < Kd) v = A[(size_t)gr * lda + gk];
      As[ak + i][ar] = v;
    }
#pragma unroll
    for (int i = 0; i < 4; i++) {
      int gk = k0 + br + 4 * i, gc = col0 + bc;
      float v = 0.f;
      if (gk < Kd && gc < N) v = B[(size_t)gk * ldb + gc];
      Bs[br + 4 * i][bc] = v;
    }
    __syncthreads();
#pragma unroll
    for (int kk = 0; kk < 16; kk++) {
      float a[4], b[4];
#pragma unroll
      for (int i = 0; i < 4; i++) a[i] = As[kk][ty * 4 + i];
#pragma unroll
      for (int j = 0; j < 4; j++) b[j] = Bs[kk][tx * 4 + j];
#pragma unroll
      for (int i = 0; i < 4; i++)
#pragma unroll
        for (int j = 0; j < 4; j++) acc[i][j] += a[i] * b[j];
    }
    __syncthreads();
  }
#pragma unroll
  for (int i = 0; i < 4; i++) {
    int r = row0 + ty * 4 + i;
    if (r >= M) continue;
#pragma unroll
    for (int j = 0; j < 4; j++) {
      int c = col0 + tx * 4 + j;
      if (c >= N) continue;
      float v = acc[i][j];
      if (bias) v += bias[c];
      if (act == 1) v = fmaxf(v, 0.f);
      else if (act == 2) v = (v > 20.f) ? v : log1pf(__expf(v));
      C[(size_t)r * ldc + c] = v;
    }
  }
}

// ---------------- router score: scores[row] = h[row,:]·Wr2 + br2 ----------------
__global__ __launch_bounds__(256) void router_score_kernel(
    const float* __restrict__ h, const float* __restrict__ Wr2,
    const float* __restrict__ br2, float* __restrict__ scores) {
  __shared__ float sh[4];
  int row = blockIdx.x;
  float v = h[(size_t)row * 256 + threadIdx.x] * Wr2[threadIdx.x];
  float s = block_sum256(v, sh);
  if (threadIdx.x == 0) scores[row] = s + br2[0];
}

// ---------------- exact top-K per batch via bitonic sort (desc, idx tiebreak) ----------------
__global__ __launch_bounds__(1024) void topk_kernel(
    const float* __restrict__ scores, int* __restrict__ idx) {
  __shared__ float s[1024];
  __shared__ int si[1024];
  int b = blockIdx.x, t = threadIdx.x;
  s[t] = scores[b * TT + t];
  si[t] = t;
  __syncthreads();
  for (int k = 2; k <= 1024; k <<= 1) {
    for (int j = k >> 1; j > 0; j >>= 1) {
      int partner = t ^ j;
      if (partner > t) {
        bool dirDesc = ((t & k) == 0);
        float s1 = s[t], s2 = s[partner];
        int i1 = si[t], i2 = si[partner];
        bool firstGreater = (s1 > s2) || (s1 == s2 && i1 < i2);
        bool doSwap = dirDesc ? !firstGreater : firstGreater;
        if (doSwap) { s[t] = s2; s[partner] = s1; si[t] = i2; si[partner] = i1; }
      }
      __syncthreads();
    }
  }
  if (t < KK) idx[b * KK + t] = si[t];
}

// ---------------- causal conv (DC=4) + silu ----------------
__global__ __launch_bounds__(256) void conv_silu_kernel(
    const float* __restrict__ uz, const float* __restrict__ conv_w,
    const float* __restrict__ conv_b, float* __restrict__ u) {
  size_t gid = (size_t)blockIdx.x * 256 + threadIdx.x;  // over B*T*DI
  int c = gid % DII;
  size_t bt = gid / DII;
  int t = bt % TT;
  int b = bt / TT;
  float sum = conv_b[c];
#pragma unroll
  for (int j = 0; j < DCC; j++) {
    int tt = t - (DCC - 1) + j;
    if (tt >= 0) sum += uz[((size_t)(b * TT + tt)) * (2 * DII) + c] * conv_w[c * DCC + j];
  }
  u[gid] = sum / (1.f + __expf(-sum));
}

// ---------------- chunked selective scan ----------------
// Recurrence per (b,di,s): h_t = exp(dt_t * a_s) * h_{t-1} + dt_t * u_t * B_t[s]
// Phase 1: per (b,chunk,di,s) lane — local scan from h=0, record final h and
//          P = prod(dA) over the chunk.
// Phase 2: per (b,di,s) — sequential fix-up over NCH chunks -> h_in per chunk.
// Phase 3: replay with correct h_in, y_t = sum_s h_t[s]*C_t[s] via 16-lane
//          shfl reduce; fuse Dskip + silu(z).
__global__ __launch_bounds__(256) void ssm_phase1(
    const float* __restrict__ dt, const float* __restrict__ proj,
    const float* __restrict__ u, const float* __restrict__ A_log,
    float* __restrict__ hloc, float* __restrict__ Pprod) {
  int gid = blockIdx.x * 256 + threadIdx.x;  // BB*NCH*DII*16 threads
  int s = gid & 15;
  int cc = gid >> 4;  // (b*NCH + chunk)*DII + di
  int di = cc % DII;
  int rem = cc / DII;
  int chunk = rem % NCH;
  int b = rem / NCH;
  float a = -__expf(A_log[di * DSS + s]);
  float h = 0.f, P = 1.f;
  int t0 = chunk * LCH;
  for (int lt = 0; lt < LCH; lt++) {
    size_t bt = (size_t)(b * TT + t0 + lt);
    float dtv = dt[bt * DII + di];
    float uv = u[bt * DII + di];
    float Bv = proj[bt * 96 + DTRR + s];
    float dA = __expf(dtv * a);
    h = dA * h + dtv * uv * Bv;
    P *= dA;
  }
  hloc[(size_t)cc * 16 + s] = h;
  Pprod[(size_t)cc * 16 + s] = P;
}

__global__ __launch_bounds__(256) void ssm_phase2(
    const float* __restrict__ hloc, const float* __restrict__ Pprod,
    float* __restrict__ hin) {
  int gid = blockIdx.x * 256 + threadIdx.x;  // BB*DII*16 threads
  int s_di = gid % (DII * 16);               // di*16 + s
  int b = gid / (DII * 16);
  float run = 0.f;
#pragma unroll
  for (int c = 0; c < NCH; c++) {
    size_t off = ((size_t)(b * NCH + c) * DII) * 16 + s_di;
    hin[off] = run;
    run = Pprod[off] * run + hloc[off];
  }
}

__global__ __launch_bounds__(256) void ssm_phase3(
    const float* __restrict__ dt, const float* __restrict__ proj,
    const float* __restrict__ u, const float* __restrict__ uz,
    const float* __restrict__ A_log, const float* __restrict__ Dskip,
    const float* __restrict__ hin, float* __restrict__ y) {
  int gid = blockIdx.x * 256 + threadIdx.x;
  int s = gid & 15;
  int cc = gid >> 4;
  int di = cc % DII;
  int rem = cc / DII;
  int chunk = rem % NCH;
  int b = rem / NCH;
  float a = -__expf(A_log[di * DSS + s]);
  float h = hin[(size_t)cc * 16 + s];
  float dsk = Dskip[di];
  int t0 = chunk * LCH;
  for (int lt = 0; lt < LCH; lt++) {
    size_t bt = (size_t)(b * TT + t0 + lt);
    float dtv = dt[bt * DII + di];
    float uv = u[bt * DII + di];
    float Bv = proj[bt * 96 + DTRR + s];
    float Cv = proj[bt * 96 + DTRR + DSS + s];
    float dA = __expf(dtv * a);
    h = dA * h + dtv * uv * Bv;
    float yp = h * Cv;
    yp += __shfl_xor(yp, 1, 64);
    yp += __shfl_xor(yp, 2, 64);
    yp += __shfl_xor(yp, 4, 64);
    yp += __shfl_xor(yp, 8, 64);
    if (s == 0) {
      float zv = uz[bt * (2 * DII) + DII + di];
      float sz = zv / (1.f + __expf(-zv));
      y[bt * DII + di] = (yp + uv * dsk) * sz;
    }
  }
}

// ---------------- gather selected tokens ----------------
__global__ __launch_bounds__(256) void gather_tok(
    const float* __restrict__ xn, const int* __restrict__ idx,
    float* __restrict__ tok) {
  int r = blockIdx.x;  // 0..BB*KK-1
  int b = r / KK;
  int tsel = idx[r];
  const float* src = xn + ((size_t)(b * TT + tsel)) * DD;
  float* dst = tok + (size_t)r * DD;
#pragma unroll
  for (int j = 0; j < 4; j++) dst[threadIdx.x + 256 * j] = src[threadIdx.x + 256 * j];
}

// ---------------- attention: one wave per (b,h,query) ----------------
__global__ __launch_bounds__(64) void attn_kernel(
    const float* __restrict__ qkv, float* __restrict__ attn_o) {
  int gid = blockIdx.x;
  int qi = gid % KK;
  int bh = gid / KK;
  int h = bh % HH;
  int b = bh / HH;
  __shared__ float qs[64];
  __shared__ float p[KK];
  int tid = threadIdx.x;
  qs[tid] = qkv[((size_t)(b * KK + qi)) * 3072 + h * 64 + tid];
  __syncthreads();
  float pmax = -1e30f;
  for (int j = tid; j < KK; j += 64) {
    const float* kr = qkv + ((size_t)(b * KK + j)) * 3072 + 1024 + h * 64;
    float s = 0.f;
#pragma unroll
    for (int d = 0; d < 64; d++) s += qs[d] * kr[d];
    s *= 0.125f;  // 1/sqrt(64)
    p[j] = s;
    pmax = fmaxf(pmax, s);
  }
  pmax = wave_max(pmax);
  __syncthreads();
  float lsum = 0.f;
  for (int j = tid; j < KK; j += 64) {
    float e = __expf(p[j] - pmax);
    p[j] = e;
    lsum += e;
  }
  lsum = wave_sum(lsum);
  __syncthreads();
  float inv = 1.f / lsum;
  float acc = 0.f;
  for (int j = 0; j < KK; j++)
    acc += p[j] * qkv[((size_t)(b * KK + j)) * 3072 + 2048 + h * 64 + tid];
  attn_o[((size_t)(b * KK + qi)) * DD + h * 64 + tid] = acc * inv;
}

// ---------------- out = x + delta_ssm ----------------
__global__ __launch_bounds__(256) void add_kernel(
    const float* __restrict__ x, const float* __restrict__ d,
    float* __restrict__ out, int n) {
  int i = blockIdx.x * 256 + threadIdx.x;
  if (i < n) out[i] = x[i] + d[i];
}

// ---------------- scatter: out[b, idx, :] = x + delta_tok ----------------
__global__ __launch_bounds__(256) void scatter_kernel(
    const float* __restrict__ x, const float* __restrict__ attnd,
    const int* __restrict__ idx, float* __restrict__ out) {
  int r = blockIdx.x;  // 0..BB*KK-1
  int b = r / KK;
  int tsel = idx[r];
  size_t drow = ((size_t)(b * TT + tsel)) * DD;
  const float* ds = attnd + (size_t)r * DD;
#pragma unroll
  for (int j = 0; j < 4; j++) {
    int c = threadIdx.x + 256 * j;
    out[drow + c] = x[drow + c] + ds[c];
  }
}

extern "C" void kernel_launch(void* const* d_in, const int* in_sizes, int n_in,
                              void* d_out, int out_size, void* d_ws, size_t ws_size,
                              hipStream_t stream) {
  const float* x = (const float*)d_in[0];
  const float* ln_g = (const float*)d_in[1];
  const float* ln_b = (const float*)d_in[2];
  const float* Wr1 = (const float*)d_in[3];
  const float* br1 = (const float*)d_in[4];
  const float* Wr2 = (const float*)d_in[5];
  const float* br2 = (const float*)d_in[6];
  const float* Wqkv = (const float*)d_in[7];
  const float* bqkv = (const float*)d_in[8];
  const float* Wo = (const float*)d_in[9];
  const float* bo = (const float*)d_in[10];
  const float* W_in = (const float*)d_in[11];
  const float* conv_w = (const float*)d_in[12];
  const float* conv_b = (const float*)d_in[13];
  const float* W_xproj = (const float*)d_in[14];
  const float* W_dt = (const float*)d_in[15];
  const float* b_dt = (const float*)d_in[16];
  const float* A_log = (const float*)d_in[17];
  const float* Dskip = (const float*)d_in[18];
  const float* W_out = (const float*)d_in[19];
  float* out = (float*)d_out;

  float* w = (float*)d_ws;
  size_t o = 0;
  float* xn = w + o;     o += (size_t)BB * TT * DD;        // 4.19M
  float* hbuf = w + o;   o += (size_t)BB * TT * 256;       // 1.05M (reused: attn delta)
  float* scores = w + o; o += (size_t)BB * TT;             // 4K
  int* idxb = (int*)(w + o); o += 1024;                    // 816 ints
  float* uzb = w + o;    o += (size_t)BB * TT * 2 * DII;   // 16.8M
  float* ub = w + o;     o += (size_t)BB * TT * DII;       // 8.39M
  float* projb = w + o;  o += (size_t)BB * TT * 96;        // 0.39M
  float* dtb = w + o;    o += (size_t)BB * TT * DII;       // 8.39M (reused: ssm delta)
  float* yb = w + o;     o += (size_t)BB * TT * DII;       // 8.39M
  float* tokb = w + o;   o += (size_t)BB * KK * DD;        // 0.84M
  float* qkvb = w + o;   o += (size_t)BB * KK * 3 * DD;    // 2.51M
  float* attno = w + o;  o += (size_t)BB * KK * DD;        // 0.84M
  float* ssmdb = dtb;   // reuse (dt dead after scan)
  float* attnd = hbuf;  // reuse (h dead after router)
  // scan scratch overlays the attention buffers (dead during scan phases):
  // 3 x BB*NCH*DII*16 = 3 x 1.048M floats <= tokb+qkvb+attno (4.18M floats)
  const size_t CHB = (size_t)BB * NCH * DII * 16;
  float* hloc = tokb;
  float* Pprod = tokb + CHB;
  float* hin = tokb + 2 * CHB;

  // 1. layernorm
  layernorm_kernel<<<BB * TT, 256, 0, stream>>>(x, ln_g, ln_b, xn);
  // 2. router
  gemm_f32<<<dim3(4, 64), 256, 0, stream>>>(xn, DD, Wr1, 256, hbuf, 256,
                                            BB * TT, 256, DD, br1, 1);
  router_score_kernel<<<BB * TT, 256, 0, stream>>>(hbuf, Wr2, br2, scores);
  topk_kernel<<<BB, 1024, 0, stream>>>(scores, idxb);
  // 3. SSM branch
  gemm_f32<<<dim3(64, 64), 256, 0, stream>>>(xn, DD, W_in, 2 * DII, uzb, 2 * DII,
                                             BB * TT, 2 * DII, DD, nullptr, 0);
  conv_silu_kernel<<<(BB * TT * DII) / 256, 256, 0, stream>>>(uzb, conv_w, conv_b, ub);
  gemm_f32<<<dim3(2, 64), 256, 0, stream>>>(ub, DII, W_xproj, 96, projb, 96,
                                            BB * TT, 96, DII, nullptr, 0);
  gemm_f32<<<dim3(32, 64), 256, 0, stream>>>(projb, 96, W_dt, DII, dtb, DII,
                                             BB * TT, DII, DTRR, b_dt, 2);
  ssm_phase1<<<(int)(CHB / 256), 256, 0, stream>>>(dtb, projb, ub, A_log, hloc, Pprod);
  ssm_phase2<<<(BB * DII * 16) / 256, 256, 0, stream>>>(hloc, Pprod, hin);
  ssm_phase3<<<(int)(CHB / 256), 256, 0, stream>>>(dtb, projb, ub, uzb, A_log,
                                                   Dskip, hin, yb);
  gemm_f32<<<dim3(16, 64), 256, 0, stream>>>(yb, DII, W_out, DD, ssmdb, DD,
                                             BB * TT, DD, DII, nullptr, 0);
  add_kernel<<<(BB * TT * DD) / 256, 256, 0, stream>>>(x, ssmdb, out, BB * TT * DD);
  // 4. attention branch on selected tokens (scan scratch dead from here)
  gather_tok<<<BB * KK, 256, 0, stream>>>(xn, idxb, tokb);
  gemm_f32<<<dim3(48, 13), 256, 0, stream>>>(tokb, DD, Wqkv, 3 * DD, qkvb, 3 * DD,
                                             BB * KK, 3 * DD, DD, bqkv, 0);
  attn_kernel<<<BB * HH * KK, 64, 0, stream>>>(qkvb, attno);
  gemm_f32<<<dim3(16, 13), 256, 0, stream>>>(attno, DD, Wo, DD, attnd, DD,
                                             BB * KK, DD, DD, bo, 0);
  // 5. scatter attention rows over ssm rows
  scatter_kernel<<<BB * KK, 256, 0, stream>>>(x, attnd, idxb, out);
}

// Round 3
// 1484.906 us; speedup vs baseline: 2.4716x; 1.8127x over previous
//
#include <hip/hip_runtime.h>
#include <hip/hip_bf16.h>
#include <math.h>

#define BB   4
#define TT   1024
#define DD   1024
#define HH   16
#define DII  2048
#define DSS  16
#define DCC  4
#define KK   204
#define HDD  64
#define DTRR 64
#define NCH  8
#define LCH  128   // TT / NCH

typedef short bf16x8 __attribute__((ext_vector_type(8)));
typedef float f32x4 __attribute__((ext_vector_type(4)));

#define GLDS16(g, l) __builtin_amdgcn_global_load_lds(                        \
    (const __attribute__((address_space(1))) void*)(g),                       \
    (__attribute__((address_space(3))) void*)(l), 16, 0, 0)

// ---------------- reduction helpers ----------------
__device__ __forceinline__ float wave_sum(float v) {
#pragma unroll
  for (int o = 32; o > 0; o >>= 1) v += __shfl_xor(v, o, 64);
  return v;
}
__device__ __forceinline__ float wave_max(float v) {
#pragma unroll
  for (int o = 32; o > 0; o >>= 1) v = fmaxf(v, __shfl_xor(v, o, 64));
  return v;
}
__device__ __forceinline__ float block_sum256(float v, volatile float* sh) {
  v = wave_sum(v);
  if ((threadIdx.x & 63) == 0) sh[threadIdx.x >> 6] = v;
  __syncthreads();
  float r = sh[0] + sh[1] + sh[2] + sh[3];
  __syncthreads();
  return r;
}

// ---------------- layernorm (writes fp32 + bf16) ----------------
__global__ __launch_bounds__(256) void layernorm_kernel(
    const float* __restrict__ x, const float* __restrict__ g,
    const float* __restrict__ be, float* __restrict__ xn,
    __hip_bfloat16* __restrict__ xnb) {
  __shared__ float sh[4];
  int row = blockIdx.x;
  const float* xr = x + (size_t)row * DD;
  float v[4];
  float s = 0.f;
#pragma unroll
  for (int i = 0; i < 4; i++) { v[i] = xr[threadIdx.x + 256 * i]; s += v[i]; }
  float mean = block_sum256(s, sh) * (1.f / DD);
  float q = 0.f;
#pragma unroll
  for (int i = 0; i < 4; i++) { float d = v[i] - mean; q += d * d; }
  float var = block_sum256(q, sh) * (1.f / DD);
  float rstd = rsqrtf(var + 1e-5f);
#pragma unroll
  for (int i = 0; i < 4; i++) {
    int c = threadIdx.x + 256 * i;
    float o = (v[i] - mean) * rstd * g[c] + be[c];
    xn[(size_t)row * DD + c] = o;
    xnb[(size_t)row * DD + c] = __float2bfloat16(o);
  }
}

// ---------------- transpose + convert: W[rows,cols] f32 -> WT[cols,rows] bf16 ----
__global__ __launch_bounds__(256) void transpose_bf16(
    const float* __restrict__ W, int rows, int cols,
    __hip_bfloat16* __restrict__ WT) {
  __shared__ float tile[32][33];
  int c0 = blockIdx.x * 32, r0 = blockIdx.y * 32;
  int tx = threadIdx.x & 31, ty = threadIdx.x >> 5;  // ty 0..7
#pragma unroll
  for (int i = 0; i < 32; i += 8)
    tile[ty + i][tx] = W[(size_t)(r0 + ty + i) * cols + c0 + tx];
  __syncthreads();
#pragma unroll
  for (int i = 0; i < 32; i += 8)
    WT[(size_t)(c0 + ty + i) * rows + r0 + tx] = __float2bfloat16(tile[tx][ty + i]);
}

// ---------------- bf16 MFMA GEMM: C[M,N] = A[M,K] @ BT[N,K]^T + bias ----------
// 128x128 tile, BK=32, 4 waves, global_load_lds staging (m97 structure).
__global__ __launch_bounds__(256) void gemm_bf16_mfma(
    const ushort* __restrict__ A, int lda,
    const ushort* __restrict__ BT, int ldbt,
    float* __restrict__ C, int ldc,
    int M, int N, int K, const float* __restrict__ bias) {
  __shared__ ushort Alds[128 * 32];
  __shared__ ushort Blds[128 * 32];
  int t = threadIdx.x;
  int wv = t >> 6;
  int lane = t & 63;
  int row0 = blockIdx.y * 128, col0 = blockIdx.x * 128;
  int wr = (wv >> 1) * 64, wc = (wv & 1) * 64;
  f32x4 acc[4][4] = {};

  // staging: thread t loads 16B of row (t>>2), k-quad (t&3)
  int srow = t >> 2;
  int sk = (t & 3) * 8;
  int ar0 = row0 + srow;       if (ar0 >= M) ar0 = M - 1;
  int ar1 = row0 + 64 + srow;  if (ar1 >= M) ar1 = M - 1;
  int br0 = col0 + srow;       if (br0 >= N) br0 = N - 1;
  int br1 = col0 + 64 + srow;  if (br1 >= N) br1 = N - 1;
  const ushort* Ag0 = A + (size_t)ar0 * lda + sk;
  const ushort* Ag1 = A + (size_t)ar1 * lda + sk;
  const ushort* Bg0 = BT + (size_t)br0 * ldbt + sk;
  const ushort* Bg1 = BT + (size_t)br1 * ldbt + sk;
  ushort* Al = Alds + wv * 512;  // wave-uniform LDS base (1024B per wave)
  ushort* Bl = Blds + wv * 512;

  int frow = lane & 15;
  int fk = (lane >> 4) * 8;

  for (int k0 = 0; k0 < K; k0 += 32) {
    GLDS16(Ag0 + k0, Al);
    GLDS16(Ag1 + k0, Al + 2048);
    GLDS16(Bg0 + k0, Bl);
    GLDS16(Bg1 + k0, Bl + 2048);
    __syncthreads();
    bf16x8 af[4], bfv[4];
#pragma unroll
    for (int m = 0; m < 4; m++)
      af[m] = *(const bf16x8*)&Alds[(wr + m * 16 + frow) * 32 + fk];
#pragma unroll
    for (int n = 0; n < 4; n++)
      bfv[n] = *(const bf16x8*)&Blds[(wc + n * 16 + frow) * 32 + fk];
#pragma unroll
    for (int m = 0; m < 4; m++)
#pragma unroll
      for (int n = 0; n < 4; n++)
        acc[m][n] = __builtin_amdgcn_mfma_f32_16x16x32_bf16(af[m], bfv[n],
                                                            acc[m][n], 0, 0, 0);
    __syncthreads();
  }
  // epilogue: C row = (lane>>4)*4 + i, col = lane&15  (m89-verified layout)
  int rbase = row0 + wr + (lane >> 4) * 4;
  int cbase = col0 + wc + (lane & 15);
#pragma unroll
  for (int n = 0; n < 4; n++) {
    int ccol = cbase + n * 16;
    if (ccol >= N) continue;
    float bi = bias ? bias[ccol] : 0.f;
#pragma unroll
    for (int m = 0; m < 4; m++) {
      int r0_ = rbase + m * 16;
#pragma unroll
      for (int i = 0; i < 4; i++) {
        int r = r0_ + i;
        if (r < M) C[(size_t)r * ldc + ccol] = acc[m][n][i] + bi;
      }
    }
  }
}

// ---------------- generic fp32 GEMM: C = act(A@B + bias) ----------------
__global__ __launch_bounds__(256) void gemm_f32(
    const float* __restrict__ A, int lda,
    const float* __restrict__ B, int ldb,
    float* __restrict__ C, int ldc,
    int M, int N, int Kd,
    const float* __restrict__ bias, int act) {
  __shared__ float As[16][65];
  __shared__ float Bs[16][65];
  int tx = threadIdx.x % 16;
  int ty = threadIdx.x / 16;
  int row0 = blockIdx.y * 64, col0 = blockIdx.x * 64;
  float acc[4][4] = {};
  int ar = threadIdx.x / 4;
  int ak = (threadIdx.x % 4) * 4;
  int bc = threadIdx.x % 64;
  int br = threadIdx.x / 64;
  for (int k0 = 0; k0 < Kd; k0 += 16) {
#pragma unroll
    for (int i = 0; i < 4; i++) {
      int gr = row0 + ar, gk = k0 + ak + i;
      float v = 0.f;
      if (gr < M && gk < Kd) v = A[(size_t)gr * lda + gk];
      As[ak + i][ar] = v;
    }
#pragma unroll
    for (int i = 0; i < 4; i++) {
      int gk = k0 + br + 4 * i, gc = col0 + bc;
      float v = 0.f;
      if (gk < Kd && gc < N) v = B[(size_t)gk * ldb + gc];
      Bs[br + 4 * i][bc] = v;
    }
    __syncthreads();
#pragma unroll
    for (int kk = 0; kk < 16; kk++) {
      float a[4], b[4];
#pragma unroll
      for (int i = 0; i < 4; i++) a[i] = As[kk][ty * 4 + i];
#pragma unroll
      for (int j = 0; j < 4; j++) b[j] = Bs[kk][tx * 4 + j];
#pragma unroll
      for (int i = 0; i < 4; i++)
#pragma unroll
        for (int j = 0; j < 4; j++) acc[i][j] += a[i] * b[j];
    }
    __syncthreads();
  }
#pragma unroll
  for (int i = 0; i < 4; i++) {
    int r = row0 + ty * 4 + i;
    if (r >= M) continue;
#pragma unroll
    for (int j = 0; j < 4; j++) {
      int c = col0 + tx * 4 + j;
      if (c >= N) continue;
      float v = acc[i][j];
      if (bias) v += bias[c];
      if (act == 1) v = fmaxf(v, 0.f);
      else if (act == 2) v = (v > 20.f) ? v : log1pf(__expf(v));
      C[(size_t)r * ldc + c] = v;
    }
  }
}

// ---------------- router score ----------------
__global__ __launch_bounds__(256) void router_score_kernel(
    const float* __restrict__ h, const float* __restrict__ Wr2,
    const float* __restrict__ br2, float* __restrict__ scores) {
  __shared__ float sh[4];
  int row = blockIdx.x;
  float v = h[(size_t)row * 256 + threadIdx.x] * Wr2[threadIdx.x];
  float s = block_sum256(v, sh);
  if (threadIdx.x == 0) scores[row] = s + br2[0];
}

// ---------------- exact top-K per batch (bitonic) ----------------
__global__ __launch_bounds__(1024) void topk_kernel(
    const float* __restrict__ scores, int* __restrict__ idx) {
  __shared__ float s[1024];
  __shared__ int si[1024];
  int b = blockIdx.x, t = threadIdx.x;
  s[t] = scores[b * TT + t];
  si[t] = t;
  __syncthreads();
  for (int k = 2; k <= 1024; k <<= 1) {
    for (int j = k >> 1; j > 0; j >>= 1) {
      int partner = t ^ j;
      if (partner > t) {
        bool dirDesc = ((t & k) == 0);
        float s1 = s[t], s2 = s[partner];
        int i1 = si[t], i2 = si[partner];
        bool firstGreater = (s1 > s2) || (s1 == s2 && i1 < i2);
        bool doSwap = dirDesc ? !firstGreater : firstGreater;
        if (doSwap) { s[t] = s2; s[partner] = s1; si[t] = i2; si[partner] = i1; }
      }
      __syncthreads();
    }
  }
  if (t < KK) idx[b * KK + t] = si[t];
}

// ---------------- causal conv (DC=4) + silu ----------------
__global__ __launch_bounds__(256) void conv_silu_kernel(
    const float* __restrict__ uz, const float* __restrict__ conv_w,
    const float* __restrict__ conv_b, float* __restrict__ u) {
  size_t gid = (size_t)blockIdx.x * 256 + threadIdx.x;
  int c = gid % DII;
  size_t bt = gid / DII;
  int t = bt % TT;
  int b = bt / TT;
  float sum = conv_b[c];
#pragma unroll
  for (int j = 0; j < DCC; j++) {
    int tt = t - (DCC - 1) + j;
    if (tt >= 0) sum += uz[((size_t)(b * TT + tt)) * (2 * DII) + c] * conv_w[c * DCC + j];
  }
  u[gid] = sum / (1.f + __expf(-sum));
}

// ---------------- chunked selective scan ----------------
__global__ __launch_bounds__(256) void ssm_phase1(
    const float* __restrict__ dt, const float* __restrict__ proj,
    const float* __restrict__ u, const float* __restrict__ A_log,
    float* __restrict__ hloc, float* __restrict__ Pprod) {
  int gid = blockIdx.x * 256 + threadIdx.x;
  int s = gid & 15;
  int cc = gid >> 4;
  int di = cc % DII;
  int rem = cc / DII;
  int chunk = rem % NCH;
  int b = rem / NCH;
  float a = -__expf(A_log[di * DSS + s]);
  float h = 0.f, P = 1.f;
  int t0 = chunk * LCH;
  for (int lt = 0; lt < LCH; lt++) {
    size_t bt = (size_t)(b * TT + t0 + lt);
    float dtv = dt[bt * DII + di];
    float uv = u[bt * DII + di];
    float Bv = proj[bt * 96 + DTRR + s];
    float dA = __expf(dtv * a);
    h = dA * h + dtv * uv * Bv;
    P *= dA;
  }
  hloc[(size_t)cc * 16 + s] = h;
  Pprod[(size_t)cc * 16 + s] = P;
}

__global__ __launch_bounds__(256) void ssm_phase2(
    const float* __restrict__ hloc, const float* __restrict__ Pprod,
    float* __restrict__ hin) {
  int gid = blockIdx.x * 256 + threadIdx.x;
  int s_di = gid % (DII * 16);
  int b = gid / (DII * 16);
  float run = 0.f;
#pragma unroll
  for (int c = 0; c < NCH; c++) {
    size_t off = ((size_t)(b * NCH + c) * DII) * 16 + s_di;
    hin[off] = run;
    run = Pprod[off] * run + hloc[off];
  }
}

__global__ __launch_bounds__(256) void ssm_phase3(
    const float* __restrict__ dt, const float* __restrict__ proj,
    const float* __restrict__ u, const float* __restrict__ uz,
    const float* __restrict__ A_log, const float* __restrict__ Dskip,
    const float* __restrict__ hin, __hip_bfloat16* __restrict__ y) {
  int gid = blockIdx.x * 256 + threadIdx.x;
  int s = gid & 15;
  int cc = gid >> 4;
  int di = cc % DII;
  int rem = cc / DII;
  int chunk = rem % NCH;
  int b = rem / NCH;
  float a = -__expf(A_log[di * DSS + s]);
  float h = hin[(size_t)cc * 16 + s];
  float dsk = Dskip[di];
  int t0 = chunk * LCH;
  for (int lt = 0; lt < LCH; lt++) {
    size_t bt = (size_t)(b * TT + t0 + lt);
    float dtv = dt[bt * DII + di];
    float uv = u[bt * DII + di];
    float Bv = proj[bt * 96 + DTRR + s];
    float Cv = proj[bt * 96 + DTRR + DSS + s];
    float dA = __expf(dtv * a);
    h = dA * h + dtv * uv * Bv;
    float yp = h * Cv;
    yp += __shfl_xor(yp, 1, 64);
    yp += __shfl_xor(yp, 2, 64);
    yp += __shfl_xor(yp, 4, 64);
    yp += __shfl_xor(yp, 8, 64);
    if (s == 0) {
      float zv = uz[bt * (2 * DII) + DII + di];
      float sz = zv / (1.f + __expf(-zv));
      y[bt * DII + di] = __float2bfloat16((yp + uv * dsk) * sz);
    }
  }
}

// ---------------- gather selected tokens (bf16) ----------------
__global__ __launch_bounds__(256) void gather_tok(
    const __hip_bfloat16* __restrict__ xnb, const int* __restrict__ idx,
    __hip_bfloat16* __restrict__ tok) {
  int r = blockIdx.x;
  int b = r / KK;
  int tsel = idx[r];
  const __hip_bfloat16* src = xnb + ((size_t)(b * TT + tsel)) * DD;
  __hip_bfloat16* dst = tok + (size_t)r * DD;
#pragma unroll
  for (int j = 0; j < 4; j++) dst[threadIdx.x + 256 * j] = src[threadIdx.x + 256 * j];
}

// ---------------- attention: one wave per (b,h,query) ----------------
__global__ __launch_bounds__(64) void attn_kernel(
    const float* __restrict__ qkv, float* __restrict__ attn_o) {
  int gid = blockIdx.x;
  int qi = gid % KK;
  int bh = gid / KK;
  int h = bh % HH;
  int b = bh / HH;
  __shared__ float qs[64];
  __shared__ float p[KK];
  int tid = threadIdx.x;
  qs[tid] = qkv[((size_t)(b * KK + qi)) * 3072 + h * 64 + tid];
  __syncthreads();
  float pmax = -1e30f;
  for (int j = tid; j < KK; j += 64) {
    const float* kr = qkv + ((size_t)(b * KK + j)) * 3072 + 1024 + h * 64;
    float s = 0.f;
#pragma unroll
    for (int d = 0; d < 64; d++) s += qs[d] * kr[d];
    s *= 0.125f;
    p[j] = s;
    pmax = fmaxf(pmax, s);
  }
  pmax = wave_max(pmax);
  __syncthreads();
  float lsum = 0.f;
  for (int j = tid; j < KK; j += 64) {
    float e = __expf(p[j] - pmax);
    p[j] = e;
    lsum += e;
  }
  lsum = wave_sum(lsum);
  __syncthreads();
  float inv = 1.f / lsum;
  float acc = 0.f;
  for (int j = 0; j < KK; j++)
    acc += p[j] * qkv[((size_t)(b * KK + j)) * 3072 + 2048 + h * 64 + tid];
  attn_o[((size_t)(b * KK + qi)) * DD + h * 64 + tid] = acc * inv;
}

// ---------------- out = x + delta_ssm ----------------
__global__ __launch_bounds__(256) void add_kernel(
    const float* __restrict__ x, const float* __restrict__ d,
    float* __restrict__ out, int n) {
  int i = blockIdx.x * 256 + threadIdx.x;
  if (i < n) out[i] = x[i] + d[i];
}

// ---------------- scatter ----------------
__global__ __launch_bounds__(256) void scatter_kernel(
    const float* __restrict__ x, const float* __restrict__ attnd,
    const int* __restrict__ idx, float* __restrict__ out) {
  int r = blockIdx.x;
  int b = r / KK;
  int tsel = idx[r];
  size_t drow = ((size_t)(b * TT + tsel)) * DD;
  const float* ds = attnd + (size_t)r * DD;
#pragma unroll
  for (int j = 0; j < 4; j++) {
    int c = threadIdx.x + 256 * j;
    out[drow + c] = x[drow + c] + ds[c];
  }
}

extern "C" void kernel_launch(void* const* d_in, const int* in_sizes, int n_in,
                              void* d_out, int out_size, void* d_ws, size_t ws_size,
                              hipStream_t stream) {
  const float* x = (const float*)d_in[0];
  const float* ln_g = (const float*)d_in[1];
  const float* ln_b = (const float*)d_in[2];
  const float* Wr1 = (const float*)d_in[3];
  const float* br1 = (const float*)d_in[4];
  const float* Wr2 = (const float*)d_in[5];
  const float* br2 = (const float*)d_in[6];
  const float* Wqkv = (const float*)d_in[7];
  const float* bqkv = (const float*)d_in[8];
  const float* Wo = (const float*)d_in[9];
  const float* bo = (const float*)d_in[10];
  const float* W_in = (const float*)d_in[11];
  const float* conv_w = (const float*)d_in[12];
  const float* conv_b = (const float*)d_in[13];
  const float* W_xproj = (const float*)d_in[14];
  const float* W_dt = (const float*)d_in[15];
  const float* b_dt = (const float*)d_in[16];
  const float* A_log = (const float*)d_in[17];
  const float* Dskip = (const float*)d_in[18];
  const float* W_out = (const float*)d_in[19];
  float* out = (float*)d_out;

  float* w = (float*)d_ws;
  size_t o = 0;
  float* xn = w + o;     o += (size_t)BB * TT * DD;          // fp32 xn
  float* hbuf = w + o;   o += (size_t)BB * TT * 256;         // router hidden / attn delta
  float* scores = w + o; o += (size_t)BB * TT;
  int* idxb = (int*)(w + o); o += 1024;
  float* uzb = w + o;    o += (size_t)BB * TT * 2 * DII;
  float* ub = w + o;     o += (size_t)BB * TT * DII;
  float* projb = w + o;  o += (size_t)BB * TT * 96;
  float* dtb = w + o;    o += (size_t)BB * TT * DII;         // dt / ssm delta (reuse)
  float* qkvb = w + o;   o += (size_t)BB * KK * 3 * DD;
  float* attno = w + o;  o += (size_t)BB * KK * DD;
  float* hloc = w + o;   o += (size_t)BB * NCH * DII * 16;
  float* Pprod = w + o;  o += (size_t)BB * NCH * DII * 16;
  float* hin = w + o;    o += (size_t)BB * NCH * DII * 16;
  // bf16 buffers (allocated in float units, /2 element packing)
  __hip_bfloat16* xnb = (__hip_bfloat16*)(w + o);   o += (size_t)BB * TT * DD / 2;
  __hip_bfloat16* yb16 = (__hip_bfloat16*)(w + o);  o += (size_t)BB * TT * DII / 2;
  __hip_bfloat16* tokb = (__hip_bfloat16*)(w + o);  o += (size_t)BB * KK * DD / 2 + 8;
  __hip_bfloat16* WinT = (__hip_bfloat16*)(w + o);  o += (size_t)(2 * DII) * DD / 2;
  __hip_bfloat16* WoutT = (__hip_bfloat16*)(w + o); o += (size_t)DD * DII / 2;
  __hip_bfloat16* WqkvT = (__hip_bfloat16*)(w + o); o += (size_t)(3 * DD) * DD / 2;
  float* ssmdb = dtb;
  float* attnd = hbuf;

  // 1. layernorm (fp32 + bf16 outputs)
  layernorm_kernel<<<BB * TT, 256, 0, stream>>>(x, ln_g, ln_b, xn, xnb);
  // weight transposes/converts (bf16 [N,K])
  transpose_bf16<<<dim3(2 * DII / 32, DD / 32), 256, 0, stream>>>(W_in, DD, 2 * DII, WinT);
  transpose_bf16<<<dim3(DD / 32, DII / 32), 256, 0, stream>>>(W_out, DII, DD, WoutT);
  transpose_bf16<<<dim3(3 * DD / 32, DD / 32), 256, 0, stream>>>(Wqkv, DD, 3 * DD, WqkvT);
  // 2. router (fp32, keeps top-K selection exact)
  gemm_f32<<<dim3(4, 64), 256, 0, stream>>>(xn, DD, Wr1, 256, hbuf, 256,
                                            BB * TT, 256, DD, br1, 1);
  router_score_kernel<<<BB * TT, 256, 0, stream>>>(hbuf, Wr2, br2, scores);
  topk_kernel<<<BB, 1024, 0, stream>>>(scores, idxb);
  // 3. SSM branch
  gemm_bf16_mfma<<<dim3(2 * DII / 128, BB * TT / 128), 256, 0, stream>>>(
      (const ushort*)xnb, DD, (const ushort*)WinT, DD, uzb, 2 * DII,
      BB * TT, 2 * DII, DD, nullptr);
  conv_silu_kernel<<<(BB * TT * DII) / 256, 256, 0, stream>>>(uzb, conv_w, conv_b, ub);
  gemm_f32<<<dim3(2, 64), 256, 0, stream>>>(ub, DII, W_xproj, 96, projb, 96,
                                            BB * TT, 96, DII, nullptr, 0);
  gemm_f32<<<dim3(32, 64), 256, 0, stream>>>(projb, 96, W_dt, DII, dtb, DII,
                                             BB * TT, DII, DTRR, b_dt, 2);
  const size_t CHB = (size_t)BB * NCH * DII * 16;
  ssm_phase1<<<(int)(CHB / 256), 256, 0, stream>>>(dtb, projb, ub, A_log, hloc, Pprod);
  ssm_phase2<<<(BB * DII * 16) / 256, 256, 0, stream>>>(hloc, Pprod, hin);
  ssm_phase3<<<(int)(CHB / 256), 256, 0, stream>>>(dtb, projb, ub, uzb, A_log,
                                                   Dskip, hin, yb16);
  gemm_bf16_mfma<<<dim3(DD / 128, BB * TT / 128), 256, 0, stream>>>(
      (const ushort*)yb16, DII, (const ushort*)WoutT, DII, ssmdb, DD,
      BB * TT, DD, DII, nullptr);
  add_kernel<<<(BB * TT * DD) / 256, 256, 0, stream>>>(x, ssmdb, out, BB * TT * DD);
  // 4. attention branch
  gather_tok<<<BB * KK, 256, 0, stream>>>(xnb, idxb, tokb);
  gemm_bf16_mfma<<<dim3(3 * DD / 128, (BB * KK + 127) / 128), 256, 0, stream>>>(
      (const ushort*)tokb, DD, (const ushort*)WqkvT, DD, qkvb, 3 * DD,
      BB * KK, 3 * DD, DD, bqkv);
  attn_kernel<<<BB * HH * KK, 64, 0, stream>>>(qkvb, attno);
  gemm_f32<<<dim3(16, 13), 256, 0, stream>>>(attno, DD, Wo, DD, attnd, DD,
                                             BB * KK, DD, DD, bo, 0);
  // 5. scatter attention rows over ssm rows
  scatter_kernel<<<BB * KK, 256, 0, stream>>>(x, attnd, idxb, out);
}

// Round 4
// 1200.402 us; speedup vs baseline: 3.0574x; 1.2370x over previous
//
#include <hip/hip_runtime.h>
#include <hip/hip_bf16.h>
#include <math.h>

#define BB   4
#define TT   1024
#define DD   1024
#define HH   16
#define DII  2048
#define DSS  16
#define DCC  4
#define KK   204
#define HDD  64
#define DTRR 64
#define NCH  8
#define LCH  128   // TT / NCH
#define KSPL 8     // split-K factor for xproj GEMM
#define XPN  96    // xproj N

typedef short bf16x8 __attribute__((ext_vector_type(8)));
typedef float f32x4 __attribute__((ext_vector_type(4)));

#define GLDS16(g, l) __builtin_amdgcn_global_load_lds(                        \
    (const __attribute__((address_space(1))) void*)(g),                       \
    (__attribute__((address_space(3))) void*)(l), 16, 0, 0)

// ---------------- reduction helpers ----------------
__device__ __forceinline__ float wave_sum(float v) {
#pragma unroll
  for (int o = 32; o > 0; o >>= 1) v += __shfl_xor(v, o, 64);
  return v;
}
__device__ __forceinline__ float wave_max(float v) {
#pragma unroll
  for (int o = 32; o > 0; o >>= 1) v = fmaxf(v, __shfl_xor(v, o, 64));
  return v;
}
__device__ __forceinline__ float block_sum256(float v, volatile float* sh) {
  v = wave_sum(v);
  if ((threadIdx.x & 63) == 0) sh[threadIdx.x >> 6] = v;
  __syncthreads();
  float r = sh[0] + sh[1] + sh[2] + sh[3];
  __syncthreads();
  return r;
}

// ---------------- layernorm (writes fp32 + bf16) ----------------
__global__ __launch_bounds__(256) void layernorm_kernel(
    const float* __restrict__ x, const float* __restrict__ g,
    const float* __restrict__ be, float* __restrict__ xn,
    __hip_bfloat16* __restrict__ xnb) {
  __shared__ float sh[4];
  int row = blockIdx.x;
  const float* xr = x + (size_t)row * DD;
  float v[4];
  float s = 0.f;
#pragma unroll
  for (int i = 0; i < 4; i++) { v[i] = xr[threadIdx.x + 256 * i]; s += v[i]; }
  float mean = block_sum256(s, sh) * (1.f / DD);
  float q = 0.f;
#pragma unroll
  for (int i = 0; i < 4; i++) { float d = v[i] - mean; q += d * d; }
  float var = block_sum256(q, sh) * (1.f / DD);
  float rstd = rsqrtf(var + 1e-5f);
#pragma unroll
  for (int i = 0; i < 4; i++) {
    int c = threadIdx.x + 256 * i;
    float o = (v[i] - mean) * rstd * g[c] + be[c];
    xn[(size_t)row * DD + c] = o;
    xnb[(size_t)row * DD + c] = __float2bfloat16(o);
  }
}

// ---------------- transpose + convert: W[rows,cols] f32 -> WT[cols,rows] bf16 ----
__global__ __launch_bounds__(256) void transpose_bf16(
    const float* __restrict__ W, int rows, int cols,
    __hip_bfloat16* __restrict__ WT) {
  __shared__ float tile[32][33];
  int c0 = blockIdx.x * 32, r0 = blockIdx.y * 32;
  int tx = threadIdx.x & 31, ty = threadIdx.x >> 5;  // ty 0..7
#pragma unroll
  for (int i = 0; i < 32; i += 8)
    tile[ty + i][tx] = W[(size_t)(r0 + ty + i) * cols + c0 + tx];
  __syncthreads();
#pragma unroll
  for (int i = 0; i < 32; i += 8)
    WT[(size_t)(c0 + ty + i) * rows + r0 + tx] = __float2bfloat16(tile[tx][ty + i]);
}

// ---------------- bf16 MFMA GEMM: C[M,N] = A[M,K] @ BT[N,K]^T + bias (+addmat) ----
// 128x128 tile, BK=32, 4 waves, global_load_lds staging (m97 structure).
__global__ __launch_bounds__(256) void gemm_bf16_mfma(
    const ushort* __restrict__ A, int lda,
    const ushort* __restrict__ BT, int ldbt,
    float* __restrict__ C, int ldc,
    int M, int N, int K, const float* __restrict__ bias,
    const float* __restrict__ addmat) {
  __shared__ ushort Alds[128 * 32];
  __shared__ ushort Blds[128 * 32];
  int t = threadIdx.x;
  int wv = t >> 6;
  int lane = t & 63;
  int row0 = blockIdx.y * 128, col0 = blockIdx.x * 128;
  int wr = (wv >> 1) * 64, wc = (wv & 1) * 64;
  f32x4 acc[4][4] = {};

  int srow = t >> 2;
  int sk = (t & 3) * 8;
  int ar0 = row0 + srow;       if (ar0 >= M) ar0 = M - 1;
  int ar1 = row0 + 64 + srow;  if (ar1 >= M) ar1 = M - 1;
  int br0 = col0 + srow;       if (br0 >= N) br0 = N - 1;
  int br1 = col0 + 64 + srow;  if (br1 >= N) br1 = N - 1;
  const ushort* Ag0 = A + (size_t)ar0 * lda + sk;
  const ushort* Ag1 = A + (size_t)ar1 * lda + sk;
  const ushort* Bg0 = BT + (size_t)br0 * ldbt + sk;
  const ushort* Bg1 = BT + (size_t)br1 * ldbt + sk;
  ushort* Al = Alds + wv * 512;
  ushort* Bl = Blds + wv * 512;

  int frow = lane & 15;
  int fk = (lane >> 4) * 8;

  for (int k0 = 0; k0 < K; k0 += 32) {
    GLDS16(Ag0 + k0, Al);
    GLDS16(Ag1 + k0, Al + 2048);
    GLDS16(Bg0 + k0, Bl);
    GLDS16(Bg1 + k0, Bl + 2048);
    __syncthreads();
    bf16x8 af[4], bfv[4];
#pragma unroll
    for (int m = 0; m < 4; m++)
      af[m] = *(const bf16x8*)&Alds[(wr + m * 16 + frow) * 32 + fk];
#pragma unroll
    for (int n = 0; n < 4; n++)
      bfv[n] = *(const bf16x8*)&Blds[(wc + n * 16 + frow) * 32 + fk];
#pragma unroll
    for (int m = 0; m < 4; m++)
#pragma unroll
      for (int n = 0; n < 4; n++)
        acc[m][n] = __builtin_amdgcn_mfma_f32_16x16x32_bf16(af[m], bfv[n],
                                                            acc[m][n], 0, 0, 0);
    __syncthreads();
  }
  int rbase = row0 + wr + (lane >> 4) * 4;
  int cbase = col0 + wc + (lane & 15);
#pragma unroll
  for (int n = 0; n < 4; n++) {
    int ccol = cbase + n * 16;
    if (ccol >= N) continue;
    float bi = bias ? bias[ccol] : 0.f;
#pragma unroll
    for (int m = 0; m < 4; m++) {
      int r0_ = rbase + m * 16;
#pragma unroll
      for (int i = 0; i < 4; i++) {
        int r = r0_ + i;
        if (r < M) {
          float v = acc[m][n][i] + bi;
          if (addmat) v += addmat[(size_t)r * ldc + ccol];
          C[(size_t)r * ldc + ccol] = v;
        }
      }
    }
  }
}

// ---------------- generic fp32 GEMM: C = act(A@B + bias) ----------------
__global__ __launch_bounds__(256) void gemm_f32(
    const float* __restrict__ A, int lda,
    const float* __restrict__ B, int ldb,
    float* __restrict__ C, int ldc,
    int M, int N, int Kd,
    const float* __restrict__ bias, int act) {
  __shared__ float As[16][65];
  __shared__ float Bs[16][65];
  int tx = threadIdx.x % 16;
  int ty = threadIdx.x / 16;
  int row0 = blockIdx.y * 64, col0 = blockIdx.x * 64;
  float acc[4][4] = {};
  int ar = threadIdx.x / 4;
  int ak = (threadIdx.x % 4) * 4;
  int bc = threadIdx.x % 64;
  int br = threadIdx.x / 64;
  for (int k0 = 0; k0 < Kd; k0 += 16) {
#pragma unroll
    for (int i = 0; i < 4; i++) {
      int gr = row0 + ar, gk = k0 + ak + i;
      float v = 0.f;
      if (gr < M && gk < Kd) v = A[(size_t)gr * lda + gk];
      As[ak + i][ar] = v;
    }
#pragma unroll
    for (int i = 0; i < 4; i++) {
      int gk = k0 + br + 4 * i, gc = col0 + bc;
      float v = 0.f;
      if (gk < Kd && gc < N) v = B[(size_t)gk * ldb + gc];
      Bs[br + 4 * i][bc] = v;
    }
    __syncthreads();
#pragma unroll
    for (int kk = 0; kk < 16; kk++) {
      float a[4], b[4];
#pragma unroll
      for (int i = 0; i < 4; i++) a[i] = As[kk][ty * 4 + i];
#pragma unroll
      for (int j = 0; j < 4; j++) b[j] = Bs[kk][tx * 4 + j];
#pragma unroll
      for (int i = 0; i < 4; i++)
#pragma unroll
        for (int j = 0; j < 4; j++) acc[i][j] += a[i] * b[j];
    }
    __syncthreads();
  }
#pragma unroll
  for (int i = 0; i < 4; i++) {
    int r = row0 + ty * 4 + i;
    if (r >= M) continue;
#pragma unroll
    for (int j = 0; j < 4; j++) {
      int c = col0 + tx * 4 + j;
      if (c >= N) continue;
      float v = acc[i][j];
      if (bias) v += bias[c];
      if (act == 1) v = fmaxf(v, 0.f);
      else if (act == 2) v = (v > 20.f) ? v : log1pf(__expf(v));
      C[(size_t)r * ldc + c] = v;
    }
  }
}

// ---------------- split-K fp32 GEMM (for skinny-N): partial[ks] = A@B chunk ----
__global__ __launch_bounds__(256) void gemm_f32_splitk(
    const float* __restrict__ A, int lda,
    const float* __restrict__ B, int ldb,
    float* __restrict__ partial,  // [KSPL][M][N]
    int M, int N, int Kd) {
  __shared__ float As[16][65];
  __shared__ float Bs[16][65];
  int tx = threadIdx.x % 16;
  int ty = threadIdx.x / 16;
  int row0 = blockIdx.y * 64, col0 = blockIdx.x * 64;
  int ks = blockIdx.z;
  int kchunk = Kd / KSPL;
  int kbeg = ks * kchunk, kend = kbeg + kchunk;
  float acc[4][4] = {};
  int ar = threadIdx.x / 4;
  int ak = (threadIdx.x % 4) * 4;
  int bc = threadIdx.x % 64;
  int br = threadIdx.x / 64;
  for (int k0 = kbeg; k0 < kend; k0 += 16) {
#pragma unroll
    for (int i = 0; i < 4; i++) {
      int gr = row0 + ar, gk = k0 + ak + i;
      float v = 0.f;
      if (gr < M) v = A[(size_t)gr * lda + gk];
      As[ak + i][ar] = v;
    }
#pragma unroll
    for (int i = 0; i < 4; i++) {
      int gk = k0 + br + 4 * i, gc = col0 + bc;
      float v = 0.f;
      if (gc < N) v = B[(size_t)gk * ldb + gc];
      Bs[br + 4 * i][bc] = v;
    }
    __syncthreads();
#pragma unroll
    for (int kk = 0; kk < 16; kk++) {
      float a[4], b[4];
#pragma unroll
      for (int i = 0; i < 4; i++) a[i] = As[kk][ty * 4 + i];
#pragma unroll
      for (int j = 0; j < 4; j++) b[j] = Bs[kk][tx * 4 + j];
#pragma unroll
      for (int i = 0; i < 4; i++)
#pragma unroll
        for (int j = 0; j < 4; j++) acc[i][j] += a[i] * b[j];
    }
    __syncthreads();
  }
  float* P = partial + (size_t)ks * M * N;
#pragma unroll
  for (int i = 0; i < 4; i++) {
    int r = row0 + ty * 4 + i;
    if (r >= M) continue;
#pragma unroll
    for (int j = 0; j < 4; j++) {
      int c = col0 + tx * 4 + j;
      if (c < N) P[(size_t)r * N + c] = acc[i][j];
    }
  }
}

__global__ __launch_bounds__(256) void splitk_reduce(
    const float* __restrict__ partial, float* __restrict__ C, int MN) {
  int i = blockIdx.x * 256 + threadIdx.x;
  if (i >= MN) return;
  float s = 0.f;
#pragma unroll
  for (int k = 0; k < KSPL; k++) s += partial[(size_t)k * MN + i];
  C[i] = s;
}

// ---------------- router score ----------------
__global__ __launch_bounds__(256) void router_score_kernel(
    const float* __restrict__ h, const float* __restrict__ Wr2,
    const float* __restrict__ br2, float* __restrict__ scores) {
  __shared__ float sh[4];
  int row = blockIdx.x;
  float v = h[(size_t)row * 256 + threadIdx.x] * Wr2[threadIdx.x];
  float s = block_sum256(v, sh);
  if (threadIdx.x == 0) scores[row] = s + br2[0];
}

// ---------------- exact top-K per batch (bitonic) ----------------
__global__ __launch_bounds__(1024) void topk_kernel(
    const float* __restrict__ scores, int* __restrict__ idx) {
  __shared__ float s[1024];
  __shared__ int si[1024];
  int b = blockIdx.x, t = threadIdx.x;
  s[t] = scores[b * TT + t];
  si[t] = t;
  __syncthreads();
  for (int k = 2; k <= 1024; k <<= 1) {
    for (int j = k >> 1; j > 0; j >>= 1) {
      int partner = t ^ j;
      if (partner > t) {
        bool dirDesc = ((t & k) == 0);
        float s1 = s[t], s2 = s[partner];
        int i1 = si[t], i2 = si[partner];
        bool firstGreater = (s1 > s2) || (s1 == s2 && i1 < i2);
        bool doSwap = dirDesc ? !firstGreater : firstGreater;
        if (doSwap) { s[t] = s2; s[partner] = s1; si[t] = i2; si[partner] = i1; }
      }
      __syncthreads();
    }
  }
  if (t < KK) idx[b * KK + t] = si[t];
}

// ---------------- causal conv (DC=4) + silu ----------------
__global__ __launch_bounds__(256) void conv_silu_kernel(
    const float* __restrict__ uz, const float* __restrict__ conv_w,
    const float* __restrict__ conv_b, float* __restrict__ u) {
  size_t gid = (size_t)blockIdx.x * 256 + threadIdx.x;
  int c = gid % DII;
  size_t bt = gid / DII;
  int t = bt % TT;
  int b = bt / TT;
  float sum = conv_b[c];
#pragma unroll
  for (int j = 0; j < DCC; j++) {
    int tt = t - (DCC - 1) + j;
    if (tt >= 0) sum += uz[((size_t)(b * TT + tt)) * (2 * DII) + c] * conv_w[c * DCC + j];
  }
  u[gid] = sum / (1.f + __expf(-sum));
}

// ---------------- chunked selective scan ----------------
__global__ __launch_bounds__(256) void ssm_phase1(
    const float* __restrict__ dt, const float* __restrict__ proj,
    const float* __restrict__ u, const float* __restrict__ A_log,
    float* __restrict__ hloc, float* __restrict__ Pprod) {
  int gid = blockIdx.x * 256 + threadIdx.x;
  int s = gid & 15;
  int cc = gid >> 4;
  int di = cc % DII;
  int rem = cc / DII;
  int chunk = rem % NCH;
  int b = rem / NCH;
  float a = -__expf(A_log[di * DSS + s]);
  float h = 0.f, P = 1.f;
  int t0 = chunk * LCH;
  for (int lt = 0; lt < LCH; lt++) {
    size_t bt = (size_t)(b * TT + t0 + lt);
    float dtv = dt[bt * DII + di];
    float uv = u[bt * DII + di];
    float Bv = proj[bt * 96 + DTRR + s];
    float dA = __expf(dtv * a);
    h = dA * h + dtv * uv * Bv;
    P *= dA;
  }
  hloc[(size_t)cc * 16 + s] = h;
  Pprod[(size_t)cc * 16 + s] = P;
}

__global__ __launch_bounds__(256) void ssm_phase2(
    const float* __restrict__ hloc, const float* __restrict__ Pprod,
    float* __restrict__ hin) {
  int gid = blockIdx.x * 256 + threadIdx.x;
  int s_di = gid % (DII * 16);
  int b = gid / (DII * 16);
  float run = 0.f;
#pragma unroll
  for (int c = 0; c < NCH; c++) {
    size_t off = ((size_t)(b * NCH + c) * DII) * 16 + s_di;
    hin[off] = run;
    run = Pprod[off] * run + hloc[off];
  }
}

__global__ __launch_bounds__(256) void ssm_phase3(
    const float* __restrict__ dt, const float* __restrict__ proj,
    const float* __restrict__ u, const float* __restrict__ uz,
    const float* __restrict__ A_log, const float* __restrict__ Dskip,
    const float* __restrict__ hin, __hip_bfloat16* __restrict__ y) {
  int gid = blockIdx.x * 256 + threadIdx.x;
  int s = gid & 15;
  int cc = gid >> 4;
  int di = cc % DII;
  int rem = cc / DII;
  int chunk = rem % NCH;
  int b = rem / NCH;
  float a = -__expf(A_log[di * DSS + s]);
  float h = hin[(size_t)cc * 16 + s];
  float dsk = Dskip[di];
  int t0 = chunk * LCH;
  for (int lt = 0; lt < LCH; lt++) {
    size_t bt = (size_t)(b * TT + t0 + lt);
    float dtv = dt[bt * DII + di];
    float uv = u[bt * DII + di];
    float Bv = proj[bt * 96 + DTRR + s];
    float Cv = proj[bt * 96 + DTRR + DSS + s];
    float dA = __expf(dtv * a);
    h = dA * h + dtv * uv * Bv;
    float yp = h * Cv;
    yp += __shfl_xor(yp, 1, 64);
    yp += __shfl_xor(yp, 2, 64);
    yp += __shfl_xor(yp, 4, 64);
    yp += __shfl_xor(yp, 8, 64);
    if (s == 0) {
      float zv = uz[bt * (2 * DII) + DII + di];
      float sz = zv / (1.f + __expf(-zv));
      y[bt * DII + di] = __float2bfloat16((yp + uv * dsk) * sz);
    }
  }
}

// ---------------- gather selected tokens (bf16) ----------------
__global__ __launch_bounds__(256) void gather_tok(
    const __hip_bfloat16* __restrict__ xnb, const int* __restrict__ idx,
    __hip_bfloat16* __restrict__ tok) {
  int r = blockIdx.x;
  int b = r / KK;
  int tsel = idx[r];
  const __hip_bfloat16* src = xnb + ((size_t)(b * TT + tsel)) * DD;
  __hip_bfloat16* dst = tok + (size_t)r * DD;
#pragma unroll
  for (int j = 0; j < 4; j++) dst[threadIdx.x + 256 * j] = src[threadIdx.x + 256 * j];
}

// ---------------- attention: one wave per (b,h,query) ----------------
__global__ __launch_bounds__(64) void attn_kernel(
    const float* __restrict__ qkv, float* __restrict__ attn_o) {
  int gid = blockIdx.x;
  int qi = gid % KK;
  int bh = gid / KK;
  int h = bh % HH;
  int b = bh / HH;
  __shared__ float qs[64];
  __shared__ float p[KK];
  int tid = threadIdx.x;
  qs[tid] = qkv[((size_t)(b * KK + qi)) * 3072 + h * 64 + tid];
  __syncthreads();
  float pmax = -1e30f;
  for (int j = tid; j < KK; j += 64) {
    const float* kr = qkv + ((size_t)(b * KK + j)) * 3072 + 1024 + h * 64;
    float s = 0.f;
#pragma unroll
    for (int d = 0; d < 64; d++) s += qs[d] * kr[d];
    s *= 0.125f;
    p[j] = s;
    pmax = fmaxf(pmax, s);
  }
  pmax = wave_max(pmax);
  __syncthreads();
  float lsum = 0.f;
  for (int j = tid; j < KK; j += 64) {
    float e = __expf(p[j] - pmax);
    p[j] = e;
    lsum += e;
  }
  lsum = wave_sum(lsum);
  __syncthreads();
  float inv = 1.f / lsum;
  float acc = 0.f;
  for (int j = 0; j < KK; j++)
    acc += p[j] * qkv[((size_t)(b * KK + j)) * 3072 + 2048 + h * 64 + tid];
  attn_o[((size_t)(b * KK + qi)) * DD + h * 64 + tid] = acc * inv;
}

// ---------------- scatter ----------------
__global__ __launch_bounds__(256) void scatter_kernel(
    const float* __restrict__ x, const float* __restrict__ attnd,
    const int* __restrict__ idx, float* __restrict__ out) {
  int r = blockIdx.x;
  int b = r / KK;
  int tsel = idx[r];
  size_t drow = ((size_t)(b * TT + tsel)) * DD;
  const float* ds = attnd + (size_t)r * DD;
#pragma unroll
  for (int j = 0; j < 4; j++) {
    int c = threadIdx.x + 256 * j;
    out[drow + c] = x[drow + c] + ds[c];
  }
}

extern "C" void kernel_launch(void* const* d_in, const int* in_sizes, int n_in,
                              void* d_out, int out_size, void* d_ws, size_t ws_size,
                              hipStream_t stream) {
  const float* x = (const float*)d_in[0];
  const float* ln_g = (const float*)d_in[1];
  const float* ln_b = (const float*)d_in[2];
  const float* Wr1 = (const float*)d_in[3];
  const float* br1 = (const float*)d_in[4];
  const float* Wr2 = (const float*)d_in[5];
  const float* br2 = (const float*)d_in[6];
  const float* Wqkv = (const float*)d_in[7];
  const float* bqkv = (const float*)d_in[8];
  const float* Wo = (const float*)d_in[9];
  const float* bo = (const float*)d_in[10];
  const float* W_in = (const float*)d_in[11];
  const float* conv_w = (const float*)d_in[12];
  const float* conv_b = (const float*)d_in[13];
  const float* W_xproj = (const float*)d_in[14];
  const float* W_dt = (const float*)d_in[15];
  const float* b_dt = (const float*)d_in[16];
  const float* A_log = (const float*)d_in[17];
  const float* Dskip = (const float*)d_in[18];
  const float* W_out = (const float*)d_in[19];
  float* out = (float*)d_out;

  float* w = (float*)d_ws;
  size_t o = 0;
  float* xn = w + o;     o += (size_t)BB * TT * DD;
  float* hbuf = w + o;   o += (size_t)BB * TT * 256;         // router hidden / attn delta
  float* scores = w + o; o += (size_t)BB * TT;
  int* idxb = (int*)(w + o); o += 1024;
  float* uzb = w + o;    o += (size_t)BB * TT * 2 * DII;
  float* ub = w + o;     o += (size_t)BB * TT * DII;
  float* projb = w + o;  o += (size_t)BB * TT * 96;
  float* dtb = w + o;    o += (size_t)BB * TT * DII;         // dt / ssm delta (reuse)
  float* qkvb = w + o;   o += (size_t)BB * KK * 3 * DD;
  float* attno = w + o;  o += (size_t)BB * KK * DD;
  float* hloc = w + o;   o += (size_t)BB * NCH * DII * 16;
  float* Pprod = w + o;  o += (size_t)BB * NCH * DII * 16;
  float* hin = w + o;    o += (size_t)BB * NCH * DII * 16;
  __hip_bfloat16* xnb = (__hip_bfloat16*)(w + o);   o += (size_t)BB * TT * DD / 2;
  __hip_bfloat16* yb16 = (__hip_bfloat16*)(w + o);  o += (size_t)BB * TT * DII / 2;
  __hip_bfloat16* tokb = (__hip_bfloat16*)(w + o);  o += (size_t)BB * KK * DD / 2 + 8;
  __hip_bfloat16* WinT = (__hip_bfloat16*)(w + o);  o += (size_t)(2 * DII) * DD / 2;
  __hip_bfloat16* WoutT = (__hip_bfloat16*)(w + o); o += (size_t)DD * DII / 2;
  __hip_bfloat16* WqkvT = (__hip_bfloat16*)(w + o); o += (size_t)(3 * DD) * DD / 2;
  float* attnd = hbuf;
  // split-K partials overlay qkvb+attno (dead until attention phase):
  // KSPL * M * XPN = 8 * 4096 * 96 = 3.146M floats <= 3.342M available.
  float* xpart = qkvb;

  // 1. layernorm (fp32 + bf16 outputs)
  layernorm_kernel<<<BB * TT, 256, 0, stream>>>(x, ln_g, ln_b, xn, xnb);
  // weight transposes/converts (bf16 [N,K])
  transpose_bf16<<<dim3(2 * DII / 32, DD / 32), 256, 0, stream>>>(W_in, DD, 2 * DII, WinT);
  transpose_bf16<<<dim3(DD / 32, DII / 32), 256, 0, stream>>>(W_out, DII, DD, WoutT);
  transpose_bf16<<<dim3(3 * DD / 32, DD / 32), 256, 0, stream>>>(Wqkv, DD, 3 * DD, WqkvT);
  // 2. router (fp32, keeps top-K selection exact)
  gemm_f32<<<dim3(4, 64), 256, 0, stream>>>(xn, DD, Wr1, 256, hbuf, 256,
                                            BB * TT, 256, DD, br1, 1);
  router_score_kernel<<<BB * TT, 256, 0, stream>>>(hbuf, Wr2, br2, scores);
  topk_kernel<<<BB, 1024, 0, stream>>>(scores, idxb);
  // 3. SSM branch
  gemm_bf16_mfma<<<dim3(2 * DII / 128, BB * TT / 128), 256, 0, stream>>>(
      (const ushort*)xnb, DD, (const ushort*)WinT, DD, uzb, 2 * DII,
      BB * TT, 2 * DII, DD, nullptr, nullptr);
  conv_silu_kernel<<<(BB * TT * DII) / 256, 256, 0, stream>>>(uzb, conv_w, conv_b, ub);
  // xproj: split-K fp32 (M=4096, N=96, K=2048) -> 1024 blocks
  gemm_f32_splitk<<<dim3(2, 64, KSPL), 256, 0, stream>>>(
      ub, DII, W_xproj, XPN, xpart, BB * TT, XPN, DII);
  splitk_reduce<<<(BB * TT * XPN + 255) / 256, 256, 0, stream>>>(
      xpart, projb, BB * TT * XPN);
  gemm_f32<<<dim3(32, 64), 256, 0, stream>>>(projb, 96, W_dt, DII, dtb, DII,
                                             BB * TT, DII, DTRR, b_dt, 2);
  const size_t CHB = (size_t)BB * NCH * DII * 16;
  ssm_phase1<<<(int)(CHB / 256), 256, 0, stream>>>(dtb, projb, ub, A_log, hloc, Pprod);
  ssm_phase2<<<(BB * DII * 16) / 256, 256, 0, stream>>>(hloc, Pprod, hin);
  ssm_phase3<<<(int)(CHB / 256), 256, 0, stream>>>(dtb, projb, ub, uzb, A_log,
                                                   Dskip, hin, yb16);
  // W_out MFMA with fused residual add: out = y@W_out + x
  gemm_bf16_mfma<<<dim3(DD / 128, BB * TT / 128), 256, 0, stream>>>(
      (const ushort*)yb16, DII, (const ushort*)WoutT, DII, out, DD,
      BB * TT, DD, DII, nullptr, x);
  // 4. attention branch (xpart dead from here; qkvb reused for qkv)
  gather_tok<<<BB * KK, 256, 0, stream>>>(xnb, idxb, tokb);
  gemm_bf16_mfma<<<dim3(3 * DD / 128, (BB * KK + 127) / 128), 256, 0, stream>>>(
      (const ushort*)tokb, DD, (const ushort*)WqkvT, DD, qkvb, 3 * DD,
      BB * KK, 3 * DD, DD, bqkv, nullptr);
  attn_kernel<<<BB * HH * KK, 64, 0, stream>>>(qkvb, attno);
  gemm_f32<<<dim3(16, 13), 256, 0, stream>>>(attno, DD, Wo, DD, attnd, DD,
                                             BB * KK, DD, DD, bo, 0);
  // 5. scatter attention rows over ssm rows
  scatter_kernel<<<BB * KK, 256, 0, stream>>>(x, attnd, idxb, out);
}

// Round 5
// 770.829 us; speedup vs baseline: 4.7612x; 1.5573x over previous
//
#include <hip/hip_runtime.h>
#include <hip/hip_bf16.h>
#include <math.h>

#define BB   4
#define TT   1024
#define DD   1024
#define HH   16
#define DII  2048
#define DSS  16
#define DCC  4
#define KK   204
#define HDD  64
#define DTRR 64
#define NCH  32
#define LCH  32    // TT / NCH
#define KSPL 8
#define XPN  96

typedef short bf16x8 __attribute__((ext_vector_type(8)));
typedef float f32x4 __attribute__((ext_vector_type(4)));

#define GLDS16(g, l) __builtin_amdgcn_global_load_lds(                        \
    (const __attribute__((address_space(1))) void*)(g),                       \
    (__attribute__((address_space(3))) void*)(l), 16, 0, 0)

// ---------------- reduction helpers ----------------
__device__ __forceinline__ float wave_sum(float v) {
#pragma unroll
  for (int o = 32; o > 0; o >>= 1) v += __shfl_xor(v, o, 64);
  return v;
}
__device__ __forceinline__ float wave_max(float v) {
#pragma unroll
  for (int o = 32; o > 0; o >>= 1) v = fmaxf(v, __shfl_xor(v, o, 64));
  return v;
}
__device__ __forceinline__ float block_sum256(float v, volatile float* sh) {
  v = wave_sum(v);
  if ((threadIdx.x & 63) == 0) sh[threadIdx.x >> 6] = v;
  __syncthreads();
  float r = sh[0] + sh[1] + sh[2] + sh[3];
  __syncthreads();
  return r;
}

// ---------------- layernorm (writes fp32 + bf16) ----------------
__global__ __launch_bounds__(256) void layernorm_kernel(
    const float* __restrict__ x, const float* __restrict__ g,
    const float* __restrict__ be, float* __restrict__ xn,
    __hip_bfloat16* __restrict__ xnb) {
  __shared__ float sh[4];
  int row = blockIdx.x;
  const float* xr = x + (size_t)row * DD;
  float v[4];
  float s = 0.f;
#pragma unroll
  for (int i = 0; i < 4; i++) { v[i] = xr[threadIdx.x + 256 * i]; s += v[i]; }
  float mean = block_sum256(s, sh) * (1.f / DD);
  float q = 0.f;
#pragma unroll
  for (int i = 0; i < 4; i++) { float d = v[i] - mean; q += d * d; }
  float var = block_sum256(q, sh) * (1.f / DD);
  float rstd = rsqrtf(var + 1e-5f);
#pragma unroll
  for (int i = 0; i < 4; i++) {
    int c = threadIdx.x + 256 * i;
    float o = (v[i] - mean) * rstd * g[c] + be[c];
    xn[(size_t)row * DD + c] = o;
    xnb[(size_t)row * DD + c] = __float2bfloat16(o);
  }
}

// ---------------- transpose + convert: W[rows,cols] f32 -> WT[cols,rows] bf16 ----
__global__ __launch_bounds__(256) void transpose_bf16(
    const float* __restrict__ W, int rows, int cols,
    __hip_bfloat16* __restrict__ WT) {
  __shared__ float tile[32][33];
  int c0 = blockIdx.x * 32, r0 = blockIdx.y * 32;
  int tx = threadIdx.x & 31, ty = threadIdx.x >> 5;
#pragma unroll
  for (int i = 0; i < 32; i += 8)
    tile[ty + i][tx] = W[(size_t)(r0 + ty + i) * cols + c0 + tx];
  __syncthreads();
#pragma unroll
  for (int i = 0; i < 32; i += 8)
    WT[(size_t)(c0 + ty + i) * rows + r0 + tx] = __float2bfloat16(tile[tx][ty + i]);
}

// ---------------- bf16 MFMA GEMM ----------------
// C[M,N] = A[M,K] @ BT[N,K]^T + bias (+addmat). If rowmap: output row r maps
// to (r/KK)*TT + rowmap[r] (fused top-K scatter; rows unique -> race-free).
__global__ __launch_bounds__(256) void gemm_bf16_mfma(
    const ushort* __restrict__ A, int lda,
    const ushort* __restrict__ BT, int ldbt,
    float* __restrict__ C, int ldc,
    int M, int N, int K, const float* __restrict__ bias,
    const float* __restrict__ addmat, const int* __restrict__ rowmap) {
  __shared__ ushort Alds[128 * 32];
  __shared__ ushort Blds[128 * 32];
  int t = threadIdx.x;
  int wv = t >> 6;
  int lane = t & 63;
  int row0 = blockIdx.y * 128, col0 = blockIdx.x * 128;
  int wr = (wv >> 1) * 64, wc = (wv & 1) * 64;
  f32x4 acc[4][4] = {};

  int srow = t >> 2;
  int sk = (t & 3) * 8;
  int ar0 = row0 + srow;       if (ar0 >= M) ar0 = M - 1;
  int ar1 = row0 + 64 + srow;  if (ar1 >= M) ar1 = M - 1;
  int br0 = col0 + srow;       if (br0 >= N) br0 = N - 1;
  int br1 = col0 + 64 + srow;  if (br1 >= N) br1 = N - 1;
  const ushort* Ag0 = A + (size_t)ar0 * lda + sk;
  const ushort* Ag1 = A + (size_t)ar1 * lda + sk;
  const ushort* Bg0 = BT + (size_t)br0 * ldbt + sk;
  const ushort* Bg1 = BT + (size_t)br1 * ldbt + sk;
  ushort* Al = Alds + wv * 512;
  ushort* Bl = Blds + wv * 512;

  int frow = lane & 15;
  int fk = (lane >> 4) * 8;

  for (int k0 = 0; k0 < K; k0 += 32) {
    GLDS16(Ag0 + k0, Al);
    GLDS16(Ag1 + k0, Al + 2048);
    GLDS16(Bg0 + k0, Bl);
    GLDS16(Bg1 + k0, Bl + 2048);
    __syncthreads();
    bf16x8 af[4], bfv[4];
#pragma unroll
    for (int m = 0; m < 4; m++)
      af[m] = *(const bf16x8*)&Alds[(wr + m * 16 + frow) * 32 + fk];
#pragma unroll
    for (int n = 0; n < 4; n++)
      bfv[n] = *(const bf16x8*)&Blds[(wc + n * 16 + frow) * 32 + fk];
#pragma unroll
    for (int m = 0; m < 4; m++)
#pragma unroll
      for (int n = 0; n < 4; n++)
        acc[m][n] = __builtin_amdgcn_mfma_f32_16x16x32_bf16(af[m], bfv[n],
                                                            acc[m][n], 0, 0, 0);
    __syncthreads();
  }
  int rbase = row0 + wr + (lane >> 4) * 4;
  int cbase = col0 + wc + (lane & 15);
#pragma unroll
  for (int n = 0; n < 4; n++) {
    int ccol = cbase + n * 16;
    if (ccol >= N) continue;
    float bi = bias ? bias[ccol] : 0.f;
#pragma unroll
    for (int m = 0; m < 4; m++) {
      int r0_ = rbase + m * 16;
#pragma unroll
      for (int i = 0; i < 4; i++) {
        int r = r0_ + i;
        if (r < M) {
          size_t orow = r;
          if (rowmap) orow = (size_t)((r / KK) * TT + rowmap[r]);
          float v = acc[m][n][i] + bi;
          if (addmat) v += addmat[orow * ldc + ccol];
          C[orow * ldc + ccol] = v;
        }
      }
    }
  }
}

// ---------------- generic fp32 GEMM ----------------
__global__ __launch_bounds__(256) void gemm_f32(
    const float* __restrict__ A, int lda,
    const float* __restrict__ B, int ldb,
    float* __restrict__ C, int ldc,
    int M, int N, int Kd,
    const float* __restrict__ bias, int act) {
  __shared__ float As[16][65];
  __shared__ float Bs[16][65];
  int tx = threadIdx.x % 16;
  int ty = threadIdx.x / 16;
  int row0 = blockIdx.y * 64, col0 = blockIdx.x * 64;
  float acc[4][4] = {};
  int ar = threadIdx.x / 4;
  int ak = (threadIdx.x % 4) * 4;
  int bc = threadIdx.x % 64;
  int br = threadIdx.x / 64;
  for (int k0 = 0; k0 < Kd; k0 += 16) {
#pragma unroll
    for (int i = 0; i < 4; i++) {
      int gr = row0 + ar, gk = k0 + ak + i;
      float v = 0.f;
      if (gr < M && gk < Kd) v = A[(size_t)gr * lda + gk];
      As[ak + i][ar] = v;
    }
#pragma unroll
    for (int i = 0; i < 4; i++) {
      int gk = k0 + br + 4 * i, gc = col0 + bc;
      float v = 0.f;
      if (gk < Kd && gc < N) v = B[(size_t)gk * ldb + gc];
      Bs[br + 4 * i][bc] = v;
    }
    __syncthreads();
#pragma unroll
    for (int kk = 0; kk < 16; kk++) {
      float a[4], b[4];
#pragma unroll
      for (int i = 0; i < 4; i++) a[i] = As[kk][ty * 4 + i];
#pragma unroll
      for (int j = 0; j < 4; j++) b[j] = Bs[kk][tx * 4 + j];
#pragma unroll
      for (int i = 0; i < 4; i++)
#pragma unroll
        for (int j = 0; j < 4; j++) acc[i][j] += a[i] * b[j];
    }
    __syncthreads();
  }
#pragma unroll
  for (int i = 0; i < 4; i++) {
    int r = row0 + ty * 4 + i;
    if (r >= M) continue;
#pragma unroll
    for (int j = 0; j < 4; j++) {
      int c = col0 + tx * 4 + j;
      if (c >= N) continue;
      float v = acc[i][j];
      if (bias) v += bias[c];
      if (act == 1) v = fmaxf(v, 0.f);
      else if (act == 2) v = (v > 20.f) ? v : log1pf(__expf(v));
      C[(size_t)r * ldc + c] = v;
    }
  }
}

// ---------------- split-K fp32 GEMM: partial[ks] = A@B chunk ----------------
__global__ __launch_bounds__(256) void gemm_f32_splitk(
    const float* __restrict__ A, int lda,
    const float* __restrict__ B, int ldb,
    float* __restrict__ partial,  // [KSPL][M][N]
    int M, int N, int Kd) {
  __shared__ float As[16][65];
  __shared__ float Bs[16][65];
  int tx = threadIdx.x % 16;
  int ty = threadIdx.x / 16;
  int row0 = blockIdx.y * 64, col0 = blockIdx.x * 64;
  int ks = blockIdx.z;
  int kchunk = Kd / KSPL;
  int kbeg = ks * kchunk, kend = kbeg + kchunk;
  float acc[4][4] = {};
  int ar = threadIdx.x / 4;
  int ak = (threadIdx.x % 4) * 4;
  int bc = threadIdx.x % 64;
  int br = threadIdx.x / 64;
  for (int k0 = kbeg; k0 < kend; k0 += 16) {
#pragma unroll
    for (int i = 0; i < 4; i++) {
      int gr = row0 + ar, gk = k0 + ak + i;
      float v = 0.f;
      if (gr < M) v = A[(size_t)gr * lda + gk];
      As[ak + i][ar] = v;
    }
#pragma unroll
    for (int i = 0; i < 4; i++) {
      int gk = k0 + br + 4 * i, gc = col0 + bc;
      float v = 0.f;
      if (gc < N) v = B[(size_t)gk * ldb + gc];
      Bs[br + 4 * i][bc] = v;
    }
    __syncthreads();
#pragma unroll
    for (int kk = 0; kk < 16; kk++) {
      float a[4], b[4];
#pragma unroll
      for (int i = 0; i < 4; i++) a[i] = As[kk][ty * 4 + i];
#pragma unroll
      for (int j = 0; j < 4; j++) b[j] = Bs[kk][tx * 4 + j];
#pragma unroll
      for (int i = 0; i < 4; i++)
#pragma unroll
        for (int j = 0; j < 4; j++) acc[i][j] += a[i] * b[j];
    }
    __syncthreads();
  }
  float* P = partial + (size_t)ks * M * N;
#pragma unroll
  for (int i = 0; i < 4; i++) {
    int r = row0 + ty * 4 + i;
    if (r >= M) continue;
#pragma unroll
    for (int j = 0; j < 4; j++) {
      int c = col0 + tx * 4 + j;
      if (c < N) P[(size_t)r * N + c] = acc[i][j];
    }
  }
}

__global__ __launch_bounds__(256) void splitk_reduce(
    const float* __restrict__ partial, float* __restrict__ C, int MN, int act) {
  int i = blockIdx.x * 256 + threadIdx.x;
  if (i >= MN) return;
  float s = 0.f;
#pragma unroll
  for (int k = 0; k < KSPL; k++) s += partial[(size_t)k * MN + i];
  if (act == 1) s = fmaxf(s, 0.f);
  C[i] = s;
}

// ---------------- router score ----------------
__global__ __launch_bounds__(256) void router_score_kernel(
    const float* __restrict__ h, const float* __restrict__ Wr2,
    const float* __restrict__ br2, float* __restrict__ scores) {
  __shared__ float sh[4];
  int row = blockIdx.x;
  float v = h[(size_t)row * 256 + threadIdx.x] * Wr2[threadIdx.x];
  float s = block_sum256(v, sh);
  if (threadIdx.x == 0) scores[row] = s + br2[0];
}

// ---------------- exact top-K per batch (bitonic) ----------------
__global__ __launch_bounds__(1024) void topk_kernel(
    const float* __restrict__ scores, int* __restrict__ idx) {
  __shared__ float s[1024];
  __shared__ int si[1024];
  int b = blockIdx.x, t = threadIdx.x;
  s[t] = scores[b * TT + t];
  si[t] = t;
  __syncthreads();
  for (int k = 2; k <= 1024; k <<= 1) {
    for (int j = k >> 1; j > 0; j >>= 1) {
      int partner = t ^ j;
      if (partner > t) {
        bool dirDesc = ((t & k) == 0);
        float s1 = s[t], s2 = s[partner];
        int i1 = si[t], i2 = si[partner];
        bool firstGreater = (s1 > s2) || (s1 == s2 && i1 < i2);
        bool doSwap = dirDesc ? !firstGreater : firstGreater;
        if (doSwap) { s[t] = s2; s[partner] = s1; si[t] = i2; si[partner] = i1; }
      }
      __syncthreads();
    }
  }
  if (t < KK) idx[b * KK + t] = si[t];
}

// ---------------- causal conv (DC=4) + silu ----------------
__global__ __launch_bounds__(256) void conv_silu_kernel(
    const float* __restrict__ uz, const float* __restrict__ conv_w,
    const float* __restrict__ conv_b, float* __restrict__ u) {
  size_t gid = (size_t)blockIdx.x * 256 + threadIdx.x;
  int c = gid % DII;
  size_t bt = gid / DII;
  int t = bt % TT;
  int b = bt / TT;
  float sum = conv_b[c];
#pragma unroll
  for (int j = 0; j < DCC; j++) {
    int tt = t - (DCC - 1) + j;
    if (tt >= 0) sum += uz[((size_t)(b * TT + tt)) * (2 * DII) + c] * conv_w[c * DCC + j];
  }
  u[gid] = sum / (1.f + __expf(-sum));
}

// ---------------- chunked selective scan (states in registers) ----------------
// Lane per (b,chunk,di); 16 states in regs; proj row is block-uniform (SMEM).
__global__ __launch_bounds__(256) void ssm_phase1(
    const float* __restrict__ dt, const float* __restrict__ proj,
    const float* __restrict__ u, const float* __restrict__ A_log,
    float* __restrict__ hloc, float* __restrict__ Pprod) {
  int gid = blockIdx.x * 256 + threadIdx.x;  // BB*NCH*DII
  int di = gid % DII;
  int rem = gid / DII;
  int chunk = rem % NCH;   // block-uniform
  int b = rem / NCH;       // block-uniform
  float a[DSS], h[DSS], P[DSS];
#pragma unroll
  for (int i = 0; i < 4; i++) {
    f32x4 al = *(const f32x4*)&A_log[di * DSS + i * 4];
#pragma unroll
    for (int j = 0; j < 4; j++) a[i * 4 + j] = -__expf(al[j]);
  }
#pragma unroll
  for (int s = 0; s < DSS; s++) { h[s] = 0.f; P[s] = 1.f; }
  int t0 = chunk * LCH;
  for (int lt = 0; lt < LCH; lt++) {
    size_t bt = (size_t)(b * TT + t0 + lt);
    float dtv = dt[bt * DII + di];
    float uv = u[bt * DII + di];
    const float* pr = proj + bt * 96 + DTRR;  // uniform -> s_load
    float dtu = dtv * uv;
#pragma unroll
    for (int s = 0; s < DSS; s++) {
      float dA = __expf(dtv * a[s]);
      h[s] = dA * h[s] + dtu * pr[s];
      P[s] *= dA;
    }
  }
#pragma unroll
  for (int i = 0; i < 4; i++) {
    *(f32x4*)&hloc[(size_t)gid * 16 + i * 4] = *(f32x4*)&h[i * 4];
    *(f32x4*)&Pprod[(size_t)gid * 16 + i * 4] = *(f32x4*)&P[i * 4];
  }
}

__global__ __launch_bounds__(256) void ssm_phase2(
    const float* __restrict__ hloc, const float* __restrict__ Pprod,
    float* __restrict__ hin) {
  int gid = blockIdx.x * 256 + threadIdx.x;  // BB*DII*16
  int s_di = gid % (DII * 16);
  int b = gid / (DII * 16);
  float run = 0.f;
#pragma unroll
  for (int c = 0; c < NCH; c++) {
    size_t off = ((size_t)(b * NCH + c) * DII) * 16 + s_di;
    hin[off] = run;
    run = Pprod[off] * run + hloc[off];
  }
}

__global__ __launch_bounds__(256) void ssm_phase3(
    const float* __restrict__ dt, const float* __restrict__ proj,
    const float* __restrict__ u, const float* __restrict__ uz,
    const float* __restrict__ A_log, const float* __restrict__ Dskip,
    const float* __restrict__ hin, __hip_bfloat16* __restrict__ y) {
  int gid = blockIdx.x * 256 + threadIdx.x;  // BB*NCH*DII
  int di = gid % DII;
  int rem = gid / DII;
  int chunk = rem % NCH;
  int b = rem / NCH;
  float a[DSS], h[DSS];
#pragma unroll
  for (int i = 0; i < 4; i++) {
    f32x4 al = *(const f32x4*)&A_log[di * DSS + i * 4];
    f32x4 hl = *(const f32x4*)&hin[(size_t)gid * 16 + i * 4];
#pragma unroll
    for (int j = 0; j < 4; j++) { a[i * 4 + j] = -__expf(al[j]); h[i * 4 + j] = hl[j]; }
  }
  float dsk = Dskip[di];
  int t0 = chunk * LCH;
  for (int lt = 0; lt < LCH; lt++) {
    size_t bt = (size_t)(b * TT + t0 + lt);
    float dtv = dt[bt * DII + di];
    float uv = u[bt * DII + di];
    float zv = uz[bt * (2 * DII) + DII + di];
    const float* pr = proj + bt * 96 + DTRR;  // uniform -> s_load
    float dtu = dtv * uv;
    float yp = 0.f;
#pragma unroll
    for (int s = 0; s < DSS; s++) {
      float dA = __expf(dtv * a[s]);
      h[s] = dA * h[s] + dtu * pr[s];
      yp += h[s] * pr[DSS + s];
    }
    float sz = zv / (1.f + __expf(-zv));
    y[bt * DII + di] = __float2bfloat16((yp + uv * dsk) * sz);
  }
}

// ---------------- gather selected tokens (bf16) ----------------
__global__ __launch_bounds__(256) void gather_tok(
    const __hip_bfloat16* __restrict__ xnb, const int* __restrict__ idx,
    __hip_bfloat16* __restrict__ tok) {
  int r = blockIdx.x;
  int b = r / KK;
  int tsel = idx[r];
  const __hip_bfloat16* src = xnb + ((size_t)(b * TT + tsel)) * DD;
  __hip_bfloat16* dst = tok + (size_t)r * DD;
#pragma unroll
  for (int j = 0; j < 4; j++) dst[threadIdx.x + 256 * j] = src[threadIdx.x + 256 * j];
}

// ---------------- attention: one wave per (b,h,query), bf16 out ----------------
__global__ __launch_bounds__(64) void attn_kernel(
    const float* __restrict__ qkv, __hip_bfloat16* __restrict__ attn_o) {
  int gid = blockIdx.x;
  int qi = gid % KK;
  int bh = gid / KK;
  int h = bh % HH;
  int b = bh / HH;
  __shared__ float qs[64];
  __shared__ float p[KK];
  int tid = threadIdx.x;
  qs[tid] = qkv[((size_t)(b * KK + qi)) * 3072 + h * 64 + tid];
  __syncthreads();
  float pmax = -1e30f;
  for (int j = tid; j < KK; j += 64) {
    const float* kr = qkv + ((size_t)(b * KK + j)) * 3072 + 1024 + h * 64;
    float s = 0.f;
#pragma unroll
    for (int d = 0; d < 64; d++) s += qs[d] * kr[d];
    s *= 0.125f;
    p[j] = s;
    pmax = fmaxf(pmax, s);
  }
  pmax = wave_max(pmax);
  __syncthreads();
  float lsum = 0.f;
  for (int j = tid; j < KK; j += 64) {
    float e = __expf(p[j] - pmax);
    p[j] = e;
    lsum += e;
  }
  lsum = wave_sum(lsum);
  __syncthreads();
  float inv = 1.f / lsum;
  float acc = 0.f;
  for (int j = 0; j < KK; j++)
    acc += p[j] * qkv[((size_t)(b * KK + j)) * 3072 + 2048 + h * 64 + tid];
  attn_o[((size_t)(b * KK + qi)) * DD + h * 64 + tid] = __float2bfloat16(acc * inv);
}

extern "C" void kernel_launch(void* const* d_in, const int* in_sizes, int n_in,
                              void* d_out, int out_size, void* d_ws, size_t ws_size,
                              hipStream_t stream) {
  const float* x = (const float*)d_in[0];
  const float* ln_g = (const float*)d_in[1];
  const float* ln_b = (const float*)d_in[2];
  const float* Wr1 = (const float*)d_in[3];
  const float* br1 = (const float*)d_in[4];
  const float* Wr2 = (const float*)d_in[5];
  const float* br2 = (const float*)d_in[6];
  const float* Wqkv = (const float*)d_in[7];
  const float* bqkv = (const float*)d_in[8];
  const float* Wo = (const float*)d_in[9];
  const float* bo = (const float*)d_in[10];
  const float* W_in = (const float*)d_in[11];
  const float* conv_w = (const float*)d_in[12];
  const float* conv_b = (const float*)d_in[13];
  const float* W_xproj = (const float*)d_in[14];
  const float* W_dt = (const float*)d_in[15];
  const float* b_dt = (const float*)d_in[16];
  const float* A_log = (const float*)d_in[17];
  const float* Dskip = (const float*)d_in[18];
  const float* W_out = (const float*)d_in[19];
  float* out = (float*)d_out;

  float* w = (float*)d_ws;
  size_t o = 0;
  float* xn = w + o;     o += (size_t)BB * TT * DD;
  float* hbuf = w + o;   o += (size_t)BB * TT * 256;
  float* scores = w + o; o += (size_t)BB * TT;
  int* idxb = (int*)(w + o); o += 1024;
  float* uzb = w + o;    o += (size_t)BB * TT * 2 * DII;
  float* ub = w + o;     o += (size_t)BB * TT * DII;
  float* projb = w + o;  o += (size_t)BB * TT * 96;
  float* dtb = w + o;    o += (size_t)BB * TT * DII;
  float* qkvb = w + o;   o += (size_t)BB * KK * 3 * DD;
  float* hloc = w + o;   o += (size_t)BB * NCH * DII * 16;   // 4.19M floats
  float* Pprod = w + o;  o += (size_t)BB * NCH * DII * 16;
  float* hin = w + o;    o += (size_t)BB * NCH * DII * 16;
  __hip_bfloat16* xnb = (__hip_bfloat16*)(w + o);   o += (size_t)BB * TT * DD / 2;
  __hip_bfloat16* yb16 = (__hip_bfloat16*)(w + o);  o += (size_t)BB * TT * DII / 2;
  __hip_bfloat16* tokb = (__hip_bfloat16*)(w + o);  o += (size_t)BB * KK * DD / 2 + 8;
  __hip_bfloat16* attno = (__hip_bfloat16*)(w + o); o += (size_t)BB * KK * DD / 2 + 8;
  __hip_bfloat16* WinT = (__hip_bfloat16*)(w + o);  o += (size_t)(2 * DII) * DD / 2;
  __hip_bfloat16* WoutT = (__hip_bfloat16*)(w + o); o += (size_t)DD * DII / 2;
  __hip_bfloat16* WqkvT = (__hip_bfloat16*)(w + o); o += (size_t)(3 * DD) * DD / 2;
  __hip_bfloat16* WoT = (__hip_bfloat16*)(w + o);   o += (size_t)DD * DD / 2;
  // split-K partial overlays: router -> uzb (16.8M floats, dead until W_in GEMM);
  // xproj -> qkvb (3.34M floats incl attno slack, dead until attention phase).
  float* rpart = uzb;   // needs 8*4096*256 = 8.4M floats
  float* xpart = qkvb;  // needs 8*4096*96  = 3.15M floats

  // 1. layernorm
  layernorm_kernel<<<BB * TT, 256, 0, stream>>>(x, ln_g, ln_b, xn, xnb);
  // weight transposes/converts (bf16 [N,K])
  transpose_bf16<<<dim3(2 * DII / 32, DD / 32), 256, 0, stream>>>(W_in, DD, 2 * DII, WinT);
  transpose_bf16<<<dim3(DD / 32, DII / 32), 256, 0, stream>>>(W_out, DII, DD, WoutT);
  transpose_bf16<<<dim3(3 * DD / 32, DD / 32), 256, 0, stream>>>(Wqkv, DD, 3 * DD, WqkvT);
  transpose_bf16<<<dim3(DD / 32, DD / 32), 256, 0, stream>>>(Wo, DD, DD, WoT);
  // 2. router (fp32 split-K; selection bit-exact)
  gemm_f32_splitk<<<dim3(4, 64, KSPL), 256, 0, stream>>>(
      xn, DD, Wr1, 256, rpart, BB * TT, 256, DD);
  splitk_reduce<<<(BB * TT * 256 + 255) / 256, 256, 0, stream>>>(
      rpart, hbuf, BB * TT * 256, 1);
  router_score_kernel<<<BB * TT, 256, 0, stream>>>(hbuf, Wr2, br2, scores);
  topk_kernel<<<BB, 1024, 0, stream>>>(scores, idxb);
  // 3. SSM branch
  gemm_bf16_mfma<<<dim3(2 * DII / 128, BB * TT / 128), 256, 0, stream>>>(
      (const ushort*)xnb, DD, (const ushort*)WinT, DD, uzb, 2 * DII,
      BB * TT, 2 * DII, DD, nullptr, nullptr, nullptr);
  conv_silu_kernel<<<(BB * TT * DII) / 256, 256, 0, stream>>>(uzb, conv_w, conv_b, ub);
  gemm_f32_splitk<<<dim3(2, 64, KSPL), 256, 0, stream>>>(
      ub, DII, W_xproj, XPN, xpart, BB * TT, XPN, DII);
  splitk_reduce<<<(BB * TT * XPN + 255) / 256, 256, 0, stream>>>(
      xpart, projb, BB * TT * XPN, 0);
  gemm_f32<<<dim3(32, 64), 256, 0, stream>>>(projb, 96, W_dt, DII, dtb, DII,
                                             BB * TT, DII, DTRR, b_dt, 2);
  ssm_phase1<<<(BB * NCH * DII) / 256, 256, 0, stream>>>(dtb, projb, ub, A_log,
                                                         hloc, Pprod);
  ssm_phase2<<<(BB * DII * 16) / 256, 256, 0, stream>>>(hloc, Pprod, hin);
  ssm_phase3<<<(BB * NCH * DII) / 256, 256, 0, stream>>>(dtb, projb, ub, uzb,
                                                         A_log, Dskip, hin, yb16);
  // out = y@W_out + x (fused residual)
  gemm_bf16_mfma<<<dim3(DD / 128, BB * TT / 128), 256, 0, stream>>>(
      (const ushort*)yb16, DII, (const ushort*)WoutT, DII, out, DD,
      BB * TT, DD, DII, nullptr, x, nullptr);
  // 4. attention branch (xpart dead; qkvb reused)
  gather_tok<<<BB * KK, 256, 0, stream>>>(xnb, idxb, tokb);
  gemm_bf16_mfma<<<dim3(3 * DD / 128, (BB * KK + 127) / 128), 256, 0, stream>>>(
      (const ushort*)tokb, DD, (const ushort*)WqkvT, DD, qkvb, 3 * DD,
      BB * KK, 3 * DD, DD, bqkv, nullptr, nullptr);
  attn_kernel<<<BB * HH * KK, 64, 0, stream>>>(qkvb, attno);
  // Wo MFMA with fused scatter: out[b, idx[r], :] = acc + bo + x[...]
  gemm_bf16_mfma<<<dim3(DD / 128, (BB * KK + 127) / 128), 256, 0, stream>>>(
      (const ushort*)attno, DD, (const ushort*)WoT, DD, out, DD,
      BB * KK, DD, DD, bo, x, idxb);
}

// Round 6
// 664.175 us; speedup vs baseline: 5.5258x; 1.1606x over previous
//
#include <hip/hip_runtime.h>
#include <hip/hip_bf16.h>
#include <math.h>

#define BB   4
#define TT   1024
#define DD   1024
#define HH   16
#define DII  2048
#define DSS  16
#define DCC  4
#define KK   204
#define HDD  64
#define DTRR 64
#define NCH  32
#define LCH  32    // TT / NCH
#define KSPL 8
#define XPN  96

typedef short bf16x8 __attribute__((ext_vector_type(8)));
typedef float f32x4 __attribute__((ext_vector_type(4)));

#define GLDS16(g, l) __builtin_amdgcn_global_load_lds(                        \
    (const __attribute__((address_space(1))) void*)(g),                       \
    (__attribute__((address_space(3))) void*)(l), 16, 0, 0)

__device__ __forceinline__ ushort f2bu(float v) {
  __hip_bfloat16 h = __float2bfloat16(v);
  return __builtin_bit_cast(ushort, h);
}

// ---------------- reduction helpers ----------------
__device__ __forceinline__ float wave_sum(float v) {
#pragma unroll
  for (int o = 32; o > 0; o >>= 1) v += __shfl_xor(v, o, 64);
  return v;
}
__device__ __forceinline__ float block_sum256(float v, volatile float* sh) {
  v = wave_sum(v);
  if ((threadIdx.x & 63) == 0) sh[threadIdx.x >> 6] = v;
  __syncthreads();
  float r = sh[0] + sh[1] + sh[2] + sh[3];
  __syncthreads();
  return r;
}

// ---------------- layernorm (writes fp32 + bf16) ----------------
__global__ __launch_bounds__(256) void layernorm_kernel(
    const float* __restrict__ x, const float* __restrict__ g,
    const float* __restrict__ be, float* __restrict__ xn,
    __hip_bfloat16* __restrict__ xnb) {
  __shared__ float sh[4];
  int row = blockIdx.x;
  const float* xr = x + (size_t)row * DD;
  float v[4];
  float s = 0.f;
#pragma unroll
  for (int i = 0; i < 4; i++) { v[i] = xr[threadIdx.x + 256 * i]; s += v[i]; }
  float mean = block_sum256(s, sh) * (1.f / DD);
  float q = 0.f;
#pragma unroll
  for (int i = 0; i < 4; i++) { float d = v[i] - mean; q += d * d; }
  float var = block_sum256(q, sh) * (1.f / DD);
  float rstd = rsqrtf(var + 1e-5f);
#pragma unroll
  for (int i = 0; i < 4; i++) {
    int c = threadIdx.x + 256 * i;
    float o = (v[i] - mean) * rstd * g[c] + be[c];
    xn[(size_t)row * DD + c] = o;
    xnb[(size_t)row * DD + c] = __float2bfloat16(o);
  }
}

// ---------------- transpose + convert: W[rows,cols] f32 -> WT[cols,rows] bf16 ----
__global__ __launch_bounds__(256) void transpose_bf16(
    const float* __restrict__ W, int rows, int cols,
    __hip_bfloat16* __restrict__ WT) {
  __shared__ float tile[32][33];
  int c0 = blockIdx.x * 32, r0 = blockIdx.y * 32;
  int tx = threadIdx.x & 31, ty = threadIdx.x >> 5;
#pragma unroll
  for (int i = 0; i < 32; i += 8)
    tile[ty + i][tx] = W[(size_t)(r0 + ty + i) * cols + c0 + tx];
  __syncthreads();
#pragma unroll
  for (int i = 0; i < 32; i += 8)
    WT[(size_t)(c0 + ty + i) * rows + r0 + tx] = __float2bfloat16(tile[tx][ty + i]);
}

// ---------------- bf16 MFMA GEMM ----------------
// C[M,N] = A[M,K] @ BT[N,K]^T + bias (+addmat). If rowmap: output row r maps
// to (r/KK)*TT + rowmap[r] (fused top-K scatter; rows unique -> race-free).
__global__ __launch_bounds__(256) void gemm_bf16_mfma(
    const ushort* __restrict__ A, int lda,
    const ushort* __restrict__ BT, int ldbt,
    float* __restrict__ C, int ldc,
    int M, int N, int K, const float* __restrict__ bias,
    const float* __restrict__ addmat, const int* __restrict__ rowmap) {
  __shared__ ushort Alds[128 * 32];
  __shared__ ushort Blds[128 * 32];
  int t = threadIdx.x;
  int wv = t >> 6;
  int lane = t & 63;
  int row0 = blockIdx.y * 128, col0 = blockIdx.x * 128;
  int wr = (wv >> 1) * 64, wc = (wv & 1) * 64;
  f32x4 acc[4][4] = {};

  int srow = t >> 2;
  int sk = (t & 3) * 8;
  int ar0 = row0 + srow;       if (ar0 >= M) ar0 = M - 1;
  int ar1 = row0 + 64 + srow;  if (ar1 >= M) ar1 = M - 1;
  int br0 = col0 + srow;       if (br0 >= N) br0 = N - 1;
  int br1 = col0 + 64 + srow;  if (br1 >= N) br1 = N - 1;
  const ushort* Ag0 = A + (size_t)ar0 * lda + sk;
  const ushort* Ag1 = A + (size_t)ar1 * lda + sk;
  const ushort* Bg0 = BT + (size_t)br0 * ldbt + sk;
  const ushort* Bg1 = BT + (size_t)br1 * ldbt + sk;
  ushort* Al = Alds + wv * 512;
  ushort* Bl = Blds + wv * 512;

  int frow = lane & 15;
  int fk = (lane >> 4) * 8;

  for (int k0 = 0; k0 < K; k0 += 32) {
    GLDS16(Ag0 + k0, Al);
    GLDS16(Ag1 + k0, Al + 2048);
    GLDS16(Bg0 + k0, Bl);
    GLDS16(Bg1 + k0, Bl + 2048);
    __syncthreads();
    bf16x8 af[4], bfv[4];
#pragma unroll
    for (int m = 0; m < 4; m++)
      af[m] = *(const bf16x8*)&Alds[(wr + m * 16 + frow) * 32 + fk];
#pragma unroll
    for (int n = 0; n < 4; n++)
      bfv[n] = *(const bf16x8*)&Blds[(wc + n * 16 + frow) * 32 + fk];
#pragma unroll
    for (int m = 0; m < 4; m++)
#pragma unroll
      for (int n = 0; n < 4; n++)
        acc[m][n] = __builtin_amdgcn_mfma_f32_16x16x32_bf16(af[m], bfv[n],
                                                            acc[m][n], 0, 0, 0);
    __syncthreads();
  }
  int rbase = row0 + wr + (lane >> 4) * 4;
  int cbase = col0 + wc + (lane & 15);
#pragma unroll
  for (int n = 0; n < 4; n++) {
    int ccol = cbase + n * 16;
    if (ccol >= N) continue;
    float bi = bias ? bias[ccol] : 0.f;
#pragma unroll
    for (int m = 0; m < 4; m++) {
      int r0_ = rbase + m * 16;
#pragma unroll
      for (int i = 0; i < 4; i++) {
        int r = r0_ + i;
        if (r < M) {
          size_t orow = r;
          if (rowmap) orow = (size_t)((r / KK) * TT + rowmap[r]);
          float v = acc[m][n][i] + bi;
          if (addmat) v += addmat[orow * ldc + ccol];
          C[orow * ldc + ccol] = v;
        }
      }
    }
  }
}

// ---------------- generic fp32 GEMM ----------------
__global__ __launch_bounds__(256) void gemm_f32(
    const float* __restrict__ A, int lda,
    const float* __restrict__ B, int ldb,
    float* __restrict__ C, int ldc,
    int M, int N, int Kd,
    const float* __restrict__ bias, int act) {
  __shared__ float As[16][65];
  __shared__ float Bs[16][65];
  int tx = threadIdx.x % 16;
  int ty = threadIdx.x / 16;
  int row0 = blockIdx.y * 64, col0 = blockIdx.x * 64;
  float acc[4][4] = {};
  int ar = threadIdx.x / 4;
  int ak = (threadIdx.x % 4) * 4;
  int bc = threadIdx.x % 64;
  int br = threadIdx.x / 64;
  for (int k0 = 0; k0 < Kd; k0 += 16) {
#pragma unroll
    for (int i = 0; i < 4; i++) {
      int gr = row0 + ar, gk = k0 + ak + i;
      float v = 0.f;
      if (gr < M && gk < Kd) v = A[(size_t)gr * lda + gk];
      As[ak + i][ar] = v;
    }
#pragma unroll
    for (int i = 0; i < 4; i++) {
      int gk = k0 + br + 4 * i, gc = col0 + bc;
      float v = 0.f;
      if (gk < Kd && gc < N) v = B[(size_t)gk * ldb + gc];
      Bs[br + 4 * i][bc] = v;
    }
    __syncthreads();
#pragma unroll
    for (int kk = 0; kk < 16; kk++) {
      float a[4], b[4];
#pragma unroll
      for (int i = 0; i < 4; i++) a[i] = As[kk][ty * 4 + i];
#pragma unroll
      for (int j = 0; j < 4; j++) b[j] = Bs[kk][tx * 4 + j];
#pragma unroll
      for (int i = 0; i < 4; i++)
#pragma unroll
        for (int j = 0; j < 4; j++) acc[i][j] += a[i] * b[j];
    }
    __syncthreads();
  }
#pragma unroll
  for (int i = 0; i < 4; i++) {
    int r = row0 + ty * 4 + i;
    if (r >= M) continue;
#pragma unroll
    for (int j = 0; j < 4; j++) {
      int c = col0 + tx * 4 + j;
      if (c >= N) continue;
      float v = acc[i][j];
      if (bias) v += bias[c];
      if (act == 1) v = fmaxf(v, 0.f);
      else if (act == 2) v = (v > 20.f) ? v : log1pf(__expf(v));
      C[(size_t)r * ldc + c] = v;
    }
  }
}

// ---------------- split-K fp32 GEMM: partial[ks] = A@B chunk ----------------
__global__ __launch_bounds__(256) void gemm_f32_splitk(
    const float* __restrict__ A, int lda,
    const float* __restrict__ B, int ldb,
    float* __restrict__ partial,  // [KSPL][M][N]
    int M, int N, int Kd) {
  __shared__ float As[16][65];
  __shared__ float Bs[16][65];
  int tx = threadIdx.x % 16;
  int ty = threadIdx.x / 16;
  int row0 = blockIdx.y * 64, col0 = blockIdx.x * 64;
  int ks = blockIdx.z;
  int kchunk = Kd / KSPL;
  int kbeg = ks * kchunk, kend = kbeg + kchunk;
  float acc[4][4] = {};
  int ar = threadIdx.x / 4;
  int ak = (threadIdx.x % 4) * 4;
  int bc = threadIdx.x % 64;
  int br = threadIdx.x / 64;
  for (int k0 = kbeg; k0 < kend; k0 += 16) {
#pragma unroll
    for (int i = 0; i < 4; i++) {
      int gr = row0 + ar, gk = k0 + ak + i;
      float v = 0.f;
      if (gr < M) v = A[(size_t)gr * lda + gk];
      As[ak + i][ar] = v;
    }
#pragma unroll
    for (int i = 0; i < 4; i++) {
      int gk = k0 + br + 4 * i, gc = col0 + bc;
      float v = 0.f;
      if (gc < N) v = B[(size_t)gk * ldb + gc];
      Bs[br + 4 * i][bc] = v;
    }
    __syncthreads();
#pragma unroll
    for (int kk = 0; kk < 16; kk++) {
      float a[4], b[4];
#pragma unroll
      for (int i = 0; i < 4; i++) a[i] = As[kk][ty * 4 + i];
#pragma unroll
      for (int j = 0; j < 4; j++) b[j] = Bs[kk][tx * 4 + j];
#pragma unroll
      for (int i = 0; i < 4; i++)
#pragma unroll
        for (int j = 0; j < 4; j++) acc[i][j] += a[i] * b[j];
    }
    __syncthreads();
  }
  float* P = partial + (size_t)ks * M * N;
#pragma unroll
  for (int i = 0; i < 4; i++) {
    int r = row0 + ty * 4 + i;
    if (r >= M) continue;
#pragma unroll
    for (int j = 0; j < 4; j++) {
      int c = col0 + tx * 4 + j;
      if (c < N) P[(size_t)r * N + c] = acc[i][j];
    }
  }
}

__global__ __launch_bounds__(256) void splitk_reduce(
    const float* __restrict__ partial, float* __restrict__ C, int MN, int act) {
  int i = blockIdx.x * 256 + threadIdx.x;
  if (i >= MN) return;
  float s = 0.f;
#pragma unroll
  for (int k = 0; k < KSPL; k++) s += partial[(size_t)k * MN + i];
  if (act == 1) s = fmaxf(s, 0.f);
  C[i] = s;
}

// ---------------- router score ----------------
__global__ __launch_bounds__(256) void router_score_kernel(
    const float* __restrict__ h, const float* __restrict__ Wr2,
    const float* __restrict__ br2, float* __restrict__ scores) {
  __shared__ float sh[4];
  int row = blockIdx.x;
  float v = h[(size_t)row * 256 + threadIdx.x] * Wr2[threadIdx.x];
  float s = block_sum256(v, sh);
  if (threadIdx.x == 0) scores[row] = s + br2[0];
}

// ---------------- exact top-K per batch (bitonic) ----------------
__global__ __launch_bounds__(1024) void topk_kernel(
    const float* __restrict__ scores, int* __restrict__ idx) {
  __shared__ float s[1024];
  __shared__ int si[1024];
  int b = blockIdx.x, t = threadIdx.x;
  s[t] = scores[b * TT + t];
  si[t] = t;
  __syncthreads();
  for (int k = 2; k <= 1024; k <<= 1) {
    for (int j = k >> 1; j > 0; j >>= 1) {
      int partner = t ^ j;
      if (partner > t) {
        bool dirDesc = ((t & k) == 0);
        float s1 = s[t], s2 = s[partner];
        int i1 = si[t], i2 = si[partner];
        bool firstGreater = (s1 > s2) || (s1 == s2 && i1 < i2);
        bool doSwap = dirDesc ? !firstGreater : firstGreater;
        if (doSwap) { s[t] = s2; s[partner] = s1; si[t] = i2; si[partner] = i1; }
      }
      __syncthreads();
    }
  }
  if (t < KK) idx[b * KK + t] = si[t];
}

// ---------------- causal conv (DC=4) + silu ----------------
__global__ __launch_bounds__(256) void conv_silu_kernel(
    const float* __restrict__ uz, const float* __restrict__ conv_w,
    const float* __restrict__ conv_b, float* __restrict__ u) {
  size_t gid = (size_t)blockIdx.x * 256 + threadIdx.x;
  int c = gid % DII;
  size_t bt = gid / DII;
  int t = bt % TT;
  int b = bt / TT;
  float sum = conv_b[c];
#pragma unroll
  for (int j = 0; j < DCC; j++) {
    int tt = t - (DCC - 1) + j;
    if (tt >= 0) sum += uz[((size_t)(b * TT + tt)) * (2 * DII) + c] * conv_w[c * DCC + j];
  }
  u[gid] = sum / (1.f + __expf(-sum));
}

// ---------------- chunked selective scan (states in registers) ----------------
__global__ __launch_bounds__(256) void ssm_phase1(
    const float* __restrict__ dt, const float* __restrict__ proj,
    const float* __restrict__ u, const float* __restrict__ A_log,
    float* __restrict__ hloc, float* __restrict__ Pprod) {
  int gid = blockIdx.x * 256 + threadIdx.x;  // BB*NCH*DII
  int di = gid % DII;
  int rem = gid / DII;
  int chunk = rem % NCH;
  int b = rem / NCH;
  float a[DSS], h[DSS], P[DSS];
#pragma unroll
  for (int i = 0; i < 4; i++) {
    f32x4 al = *(const f32x4*)&A_log[di * DSS + i * 4];
#pragma unroll
    for (int j = 0; j < 4; j++) a[i * 4 + j] = -__expf(al[j]);
  }
#pragma unroll
  for (int s = 0; s < DSS; s++) { h[s] = 0.f; P[s] = 1.f; }
  int t0 = chunk * LCH;
  for (int lt = 0; lt < LCH; lt++) {
    size_t bt = (size_t)(b * TT + t0 + lt);
    float dtv = dt[bt * DII + di];
    float uv = u[bt * DII + di];
    const float* pr = proj + bt * 96 + DTRR;
    float dtu = dtv * uv;
#pragma unroll
    for (int s = 0; s < DSS; s++) {
      float dA = __expf(dtv * a[s]);
      h[s] = dA * h[s] + dtu * pr[s];
      P[s] *= dA;
    }
  }
#pragma unroll
  for (int i = 0; i < 4; i++) {
    *(f32x4*)&hloc[(size_t)gid * 16 + i * 4] = *(f32x4*)&h[i * 4];
    *(f32x4*)&Pprod[(size_t)gid * 16 + i * 4] = *(f32x4*)&P[i * 4];
  }
}

__global__ __launch_bounds__(256) void ssm_phase2(
    const float* __restrict__ hloc, const float* __restrict__ Pprod,
    float* __restrict__ hin) {
  int gid = blockIdx.x * 256 + threadIdx.x;  // BB*DII*16
  int s_di = gid % (DII * 16);
  int b = gid / (DII * 16);
  float run = 0.f;
#pragma unroll
  for (int c = 0; c < NCH; c++) {
    size_t off = ((size_t)(b * NCH + c) * DII) * 16 + s_di;
    hin[off] = run;
    run = Pprod[off] * run + hloc[off];
  }
}

__global__ __launch_bounds__(256) void ssm_phase3(
    const float* __restrict__ dt, const float* __restrict__ proj,
    const float* __restrict__ u, const float* __restrict__ uz,
    const float* __restrict__ A_log, const float* __restrict__ Dskip,
    const float* __restrict__ hin, __hip_bfloat16* __restrict__ y) {
  int gid = blockIdx.x * 256 + threadIdx.x;  // BB*NCH*DII
  int di = gid % DII;
  int rem = gid / DII;
  int chunk = rem % NCH;
  int b = rem / NCH;
  float a[DSS], h[DSS];
#pragma unroll
  for (int i = 0; i < 4; i++) {
    f32x4 al = *(const f32x4*)&A_log[di * DSS + i * 4];
    f32x4 hl = *(const f32x4*)&hin[(size_t)gid * 16 + i * 4];
#pragma unroll
    for (int j = 0; j < 4; j++) { a[i * 4 + j] = -__expf(al[j]); h[i * 4 + j] = hl[j]; }
  }
  float dsk = Dskip[di];
  int t0 = chunk * LCH;
  for (int lt = 0; lt < LCH; lt++) {
    size_t bt = (size_t)(b * TT + t0 + lt);
    float dtv = dt[bt * DII + di];
    float uv = u[bt * DII + di];
    float zv = uz[bt * (2 * DII) + DII + di];
    const float* pr = proj + bt * 96 + DTRR;
    float dtu = dtv * uv;
    float yp = 0.f;
#pragma unroll
    for (int s = 0; s < DSS; s++) {
      float dA = __expf(dtv * a[s]);
      h[s] = dA * h[s] + dtu * pr[s];
      yp += h[s] * pr[DSS + s];
    }
    float sz = zv / (1.f + __expf(-zv));
    y[bt * DII + di] = __float2bfloat16((yp + uv * dsk) * sz);
  }
}

// ---------------- gather selected tokens (bf16) ----------------
__global__ __launch_bounds__(256) void gather_tok(
    const __hip_bfloat16* __restrict__ xnb, const int* __restrict__ idx,
    __hip_bfloat16* __restrict__ tok) {
  int r = blockIdx.x;
  int b = r / KK;
  int tsel = idx[r];
  const __hip_bfloat16* src = xnb + ((size_t)(b * TT + tsel)) * DD;
  __hip_bfloat16* dst = tok + (size_t)r * DD;
#pragma unroll
  for (int j = 0; j < 4; j++) dst[threadIdx.x + 256 * j] = src[threadIdx.x + 256 * j];
}

// ---------------- MFMA attention: block per (b,h), 13 waves ----------------
// Wave w owns q-rows [w*16, w*16+16). K bf16 LDS [208][72] (pad kills the
// 128B-stride bank conflict); V^T bf16 LDS [64][232]; P per-wave [16][232].
#define KP 72
#define VP 232
__global__ __launch_bounds__(832) void attn_mfma_kernel(
    const float* __restrict__ qkv, __hip_bfloat16* __restrict__ attn_o) {
  __shared__ ushort Klds[208 * KP];        // 29952 B
  __shared__ ushort VTlds[64 * VP];        // 29696 B
  __shared__ ushort Plds[13 * 16 * VP];    // 96512 B  (total 152.5 KB)
  int bh = blockIdx.x;
  int h = bh % HH, b = bh / HH;
  int t = threadIdx.x;
  const float* base = qkv + (size_t)(b * KK) * 3072 + h * 64;

  // stage K rows 0..207 (rows >= 204 zero)
  for (int i = t; i < 208 * 64; i += 832) {
    int r = i >> 6, d = i & 63;
    float v = (r < KK) ? base[(size_t)r * 3072 + 1024 + d] : 0.f;
    Klds[r * KP + d] = f2bu(v);
  }
  // stage V^T: VT[d][k], k 0..207 (k >= 204 zero)
  for (int i = t; i < 208 * 64; i += 832) {
    int r = i >> 6, d = i & 63;
    float v = (r < KK) ? base[(size_t)r * 3072 + 2048 + d] : 0.f;
    VTlds[d * VP + r] = f2bu(v);
  }
  // zero VT pad k = 208..231
  for (int i = t; i < 64 * (VP - 208); i += 832) {
    int d = i / (VP - 208), k = 208 + i % (VP - 208);
    VTlds[d * VP + k] = 0;
  }

  int wv = t >> 6, lane = t & 63;
  int q0 = wv * 16;
  // Q fragments (scale folded in): lane holds row q0+(lane&15), d (lane>>4)*8..+7 (+32*ks)
  int qrow = q0 + (lane & 15);
  if (qrow > KK - 1) qrow = KK - 1;
  const float* qptr = base + (size_t)qrow * 3072 + ((lane >> 4) * 8);
  bf16x8 qf[2];
#pragma unroll
  for (int ks = 0; ks < 2; ks++) {
    f32x4 lo = *(const f32x4*)(qptr + ks * 32);
    f32x4 hi = *(const f32x4*)(qptr + ks * 32 + 4);
#pragma unroll
    for (int j = 0; j < 4; j++) {
      qf[ks][j] = (short)f2bu(lo[j] * 0.125f);
      qf[ks][j + 4] = (short)f2bu(hi[j] * 0.125f);
    }
  }
  // zero own P pad k = 208..231
  ushort* myP = Plds + wv * 16 * VP;
  for (int i = lane; i < 16 * (VP - 208); i += 64) {
    int r = i / (VP - 208), k = 208 + i % (VP - 208);
    myP[r * VP + k] = 0;
  }
  __syncthreads();

  // S = Q @ K^T : 13 n-tiles, k-loop 2
  f32x4 sacc[13] = {};
#pragma unroll
  for (int nt = 0; nt < 13; nt++) {
#pragma unroll
    for (int ks = 0; ks < 2; ks++) {
      bf16x8 kf = *(const bf16x8*)&Klds[(nt * 16 + (lane & 15)) * KP +
                                        ks * 32 + (lane >> 4) * 8];
      sacc[nt] = __builtin_amdgcn_mfma_f32_16x16x32_bf16(qf[ks], kf, sacc[nt], 0, 0, 0);
    }
  }
  // mask invalid keys in last tile (k = 192 + (lane&15) >= 204)
  if ((lane & 15) >= 12) {
#pragma unroll
    for (int i = 0; i < 4; i++) sacc[12][i] = -1e30f;
  }
  // softmax per q-row: row = (lane>>4)*4 + i, cols spread over lane&15 x 13 tiles
  float m4[4], l4[4];
#pragma unroll
  for (int i = 0; i < 4; i++) {
    float m = sacc[0][i];
#pragma unroll
    for (int nt = 1; nt < 13; nt++) m = fmaxf(m, sacc[nt][i]);
    m = fmaxf(m, __shfl_xor(m, 1, 64));
    m = fmaxf(m, __shfl_xor(m, 2, 64));
    m = fmaxf(m, __shfl_xor(m, 4, 64));
    m = fmaxf(m, __shfl_xor(m, 8, 64));
    m4[i] = m;
  }
#pragma unroll
  for (int i = 0; i < 4; i++) {
    float ls = 0.f;
    int prow = (lane >> 4) * 4 + i;
#pragma unroll
    for (int nt = 0; nt < 13; nt++) {
      float e = __expf(sacc[nt][i] - m4[i]);
      ls += e;
      myP[prow * VP + nt * 16 + (lane & 15)] = f2bu(e);
    }
    ls += __shfl_xor(ls, 1, 64);
    ls += __shfl_xor(ls, 2, 64);
    ls += __shfl_xor(ls, 4, 64);
    ls += __shfl_xor(ls, 8, 64);
    l4[i] = ls;
  }
  // O = P @ V : 4 d-tiles x 7 k-steps
  f32x4 oacc[4] = {};
#pragma unroll
  for (int dt = 0; dt < 4; dt++) {
#pragma unroll
    for (int ks = 0; ks < 7; ks++) {
      bf16x8 pf = *(const bf16x8*)&myP[(lane & 15) * VP + ks * 32 + (lane >> 4) * 8];
      bf16x8 vf = *(const bf16x8*)&VTlds[(dt * 16 + (lane & 15)) * VP +
                                         ks * 32 + (lane >> 4) * 8];
      oacc[dt] = __builtin_amdgcn_mfma_f32_16x16x32_bf16(pf, vf, oacc[dt], 0, 0, 0);
    }
  }
  // write O: row = q0 + (lane>>4)*4 + i, col = dt*16 + (lane&15)
#pragma unroll
  for (int i = 0; i < 4; i++) {
    int row = q0 + (lane >> 4) * 4 + i;
    if (row >= KK) continue;
    float inv = 1.f / l4[i];
#pragma unroll
    for (int dt = 0; dt < 4; dt++) {
      int col = dt * 16 + (lane & 15);
      attn_o[((size_t)(b * KK + row)) * DD + h * 64 + col] =
          __float2bfloat16(oacc[dt][i] * inv);
    }
  }
}

extern "C" void kernel_launch(void* const* d_in, const int* in_sizes, int n_in,
                              void* d_out, int out_size, void* d_ws, size_t ws_size,
                              hipStream_t stream) {
  const float* x = (const float*)d_in[0];
  const float* ln_g = (const float*)d_in[1];
  const float* ln_b = (const float*)d_in[2];
  const float* Wr1 = (const float*)d_in[3];
  const float* br1 = (const float*)d_in[4];
  const float* Wr2 = (const float*)d_in[5];
  const float* br2 = (const float*)d_in[6];
  const float* Wqkv = (const float*)d_in[7];
  const float* bqkv = (const float*)d_in[8];
  const float* Wo = (const float*)d_in[9];
  const float* bo = (const float*)d_in[10];
  const float* W_in = (const float*)d_in[11];
  const float* conv_w = (const float*)d_in[12];
  const float* conv_b = (const float*)d_in[13];
  const float* W_xproj = (const float*)d_in[14];
  const float* W_dt = (const float*)d_in[15];
  const float* b_dt = (const float*)d_in[16];
  const float* A_log = (const float*)d_in[17];
  const float* Dskip = (const float*)d_in[18];
  const float* W_out = (const float*)d_in[19];
  float* out = (float*)d_out;

  float* w = (float*)d_ws;
  size_t o = 0;
  float* xn = w + o;     o += (size_t)BB * TT * DD;
  float* hbuf = w + o;   o += (size_t)BB * TT * 256;
  float* scores = w + o; o += (size_t)BB * TT;
  int* idxb = (int*)(w + o); o += 1024;
  float* uzb = w + o;    o += (size_t)BB * TT * 2 * DII;
  float* ub = w + o;     o += (size_t)BB * TT * DII;
  float* projb = w + o;  o += (size_t)BB * TT * 96;
  float* dtb = w + o;    o += (size_t)BB * TT * DII;
  float* qkvb = w + o;   o += (size_t)BB * KK * 3 * DD;
  float* hloc = w + o;   o += (size_t)BB * NCH * DII * 16;
  float* Pprod = w + o;  o += (size_t)BB * NCH * DII * 16;
  float* hin = w + o;    o += (size_t)BB * NCH * DII * 16;
  __hip_bfloat16* xnb = (__hip_bfloat16*)(w + o);   o += (size_t)BB * TT * DD / 2;
  __hip_bfloat16* yb16 = (__hip_bfloat16*)(w + o);  o += (size_t)BB * TT * DII / 2;
  __hip_bfloat16* tokb = (__hip_bfloat16*)(w + o);  o += (size_t)BB * KK * DD / 2 + 8;
  __hip_bfloat16* attno = (__hip_bfloat16*)(w + o); o += (size_t)BB * KK * DD / 2 + 8;
  __hip_bfloat16* WinT = (__hip_bfloat16*)(w + o);  o += (size_t)(2 * DII) * DD / 2;
  __hip_bfloat16* WoutT = (__hip_bfloat16*)(w + o); o += (size_t)DD * DII / 2;
  __hip_bfloat16* WqkvT = (__hip_bfloat16*)(w + o); o += (size_t)(3 * DD) * DD / 2;
  __hip_bfloat16* WoT = (__hip_bfloat16*)(w + o);   o += (size_t)DD * DD / 2;
  float* rpart = uzb;   // router split-K partials overlay (dead until W_in GEMM)
  float* xpart = qkvb;  // xproj split-K partials overlay (dead until attn phase)

  // 1. layernorm
  layernorm_kernel<<<BB * TT, 256, 0, stream>>>(x, ln_g, ln_b, xn, xnb);
  // weight transposes/converts (bf16 [N,K])
  transpose_bf16<<<dim3(2 * DII / 32, DD / 32), 256, 0, stream>>>(W_in, DD, 2 * DII, WinT);
  transpose_bf16<<<dim3(DD / 32, DII / 32), 256, 0, stream>>>(W_out, DII, DD, WoutT);
  transpose_bf16<<<dim3(3 * DD / 32, DD / 32), 256, 0, stream>>>(Wqkv, DD, 3 * DD, WqkvT);
  transpose_bf16<<<dim3(DD / 32, DD / 32), 256, 0, stream>>>(Wo, DD, DD, WoT);
  // 2. router (fp32 split-K; selection bit-exact)
  gemm_f32_splitk<<<dim3(4, 64, KSPL), 256, 0, stream>>>(
      xn, DD, Wr1, 256, rpart, BB * TT, 256, DD);
  splitk_reduce<<<(BB * TT * 256 + 255) / 256, 256, 0, stream>>>(
      rpart, hbuf, BB * TT * 256, 1);
  router_score_kernel<<<BB * TT, 256, 0, stream>>>(hbuf, Wr2, br2, scores);
  topk_kernel<<<BB, 1024, 0, stream>>>(scores, idxb);
  // 3. SSM branch
  gemm_bf16_mfma<<<dim3(2 * DII / 128, BB * TT / 128), 256, 0, stream>>>(
      (const ushort*)xnb, DD, (const ushort*)WinT, DD, uzb, 2 * DII,
      BB * TT, 2 * DII, DD, nullptr, nullptr, nullptr);
  conv_silu_kernel<<<(BB * TT * DII) / 256, 256, 0, stream>>>(uzb, conv_w, conv_b, ub);
  gemm_f32_splitk<<<dim3(2, 64, KSPL), 256, 0, stream>>>(
      ub, DII, W_xproj, XPN, xpart, BB * TT, XPN, DII);
  splitk_reduce<<<(BB * TT * XPN + 255) / 256, 256, 0, stream>>>(
      xpart, projb, BB * TT * XPN, 0);
  gemm_f32<<<dim3(32, 64), 256, 0, stream>>>(projb, 96, W_dt, DII, dtb, DII,
                                             BB * TT, DII, DTRR, b_dt, 2);
  ssm_phase1<<<(BB * NCH * DII) / 256, 256, 0, stream>>>(dtb, projb, ub, A_log,
                                                         hloc, Pprod);
  ssm_phase2<<<(BB * DII * 16) / 256, 256, 0, stream>>>(hloc, Pprod, hin);
  ssm_phase3<<<(BB * NCH * DII) / 256, 256, 0, stream>>>(dtb, projb, ub, uzb,
                                                         A_log, Dskip, hin, yb16);
  // out = y@W_out + x (fused residual)
  gemm_bf16_mfma<<<dim3(DD / 128, BB * TT / 128), 256, 0, stream>>>(
      (const ushort*)yb16, DII, (const ushort*)WoutT, DII, out, DD,
      BB * TT, DD, DII, nullptr, x, nullptr);
  // 4. attention branch (xpart dead; qkvb reused)
  gather_tok<<<BB * KK, 256, 0, stream>>>(xnb, idxb, tokb);
  gemm_bf16_mfma<<<dim3(3 * DD / 128, (BB * KK + 127) / 128), 256, 0, stream>>>(
      (const ushort*)tokb, DD, (const ushort*)WqkvT, DD, qkvb, 3 * DD,
      BB * KK, 3 * DD, DD, bqkv, nullptr, nullptr);
  attn_mfma_kernel<<<BB * HH, 832, 0, stream>>>(qkvb, attno);
  // Wo MFMA with fused scatter: out[b, idx[r], :] = acc + bo + x[...]
  gemm_bf16_mfma<<<dim3(DD / 128, (BB * KK + 127) / 128), 256, 0, stream>>>(
      (const ushort*)attno, DD, (const ushort*)WoT, DD, out, DD,
      BB * KK, DD, DD, bo, x, idxb);
}